// Round 4
// baseline (481.565 us; speedup 1.0000x reference)
//
#include <hip/hip_runtime.h>

#define TT   2048
#define DD   4096
#define NH   32
#define NKVH 8
#define HDM  128
#define KD   4096
#define NQKV 6144

typedef unsigned short u16;
typedef short v8s __attribute__((ext_vector_type(8)));
typedef float v4f __attribute__((ext_vector_type(4)));

// Q pre-scale: 1/sqrt(128) * log2(e)  (log2e folded so attn uses bare exp2)
#define QSCALE 0.12751744547734565f
// fixed softmax max: 12 * log2(e). Valid because |S| <= |q||k|/sqrt(128) = 11.32
#define EOFF   17.312340490667562f

__device__ __forceinline__ u16 f2bf(float f) {
    unsigned u = __builtin_bit_cast(unsigned, f);
    u += 0x7fffu + ((u >> 16) & 1u);   // round-to-nearest-even
    return (u16)(u >> 16);
}
__device__ __forceinline__ float bf2f(u16 h) {
    return __builtin_bit_cast(float, ((unsigned)h) << 16);
}
__device__ __forceinline__ void gl2lds16(const void* g, void* l) {
    // async global->LDS, 16B/lane; LDS dest = wave-uniform base + lane*16
    using gv = const __attribute__((address_space(1))) void;
    using lv = __attribute__((address_space(3))) void;
    __builtin_amdgcn_global_load_lds((gv*)g, (lv*)l, 16, 0, 0);
}

// -------- 64x64 transpose+cast tile: out[n][k] = bf16(in[k][n]) --------
__device__ __forceinline__ void transpose_tile64(const float* __restrict__ in,
                                                 u16* __restrict__ out,
                                                 int K, int N, int n0, int k0,
                                                 float* tile, int t) {
    int rc = t >> 4, cc = (t & 15) * 4;
#pragma unroll
    for (int p = 0; p < 4; ++p) {
        int k = p * 16 + rc;
        float4 v = *(const float4*)&in[(size_t)(k0 + k) * N + n0 + cc];
        tile[k * 65 + cc] = v.x; tile[k * 65 + cc + 1] = v.y;
        tile[k * 65 + cc + 2] = v.z; tile[k * 65 + cc + 3] = v.w;
    }
    __syncthreads();
    int rn = t >> 3, ck = (t & 7) * 8;
#pragma unroll
    for (int p = 0; p < 2; ++p) {
        int n = p * 32 + rn;
        v8s tv;
#pragma unroll
        for (int j = 0; j < 8; ++j) tv[j] = (short)f2bf(tile[(ck + j) * 65 + n]);
        *(v8s*)&out[(size_t)(n0 + n) * K + k0 + ck] = tv;
    }
}

// ------- prep_all: hidden cast (0..4095) + RoPE tab (4096..4607) + w_qkv^T (4608..10751) -------
__global__ __launch_bounds__(256) void prep_all_kernel(const float* __restrict__ hidden,
                                                       u16* __restrict__ hid_bf,
                                                       const int* __restrict__ positions,
                                                       float* __restrict__ cosT,
                                                       float* __restrict__ sinT,
                                                       const float* __restrict__ w_qkv,
                                                       u16* __restrict__ wqkv_t) {
    __shared__ float tile[64 * 65];
    int b = blockIdx.x;
    if (b < 4096) {
        size_t i = ((size_t)b * 256 + threadIdx.x) * 8;
        float4 a = *(const float4*)&hidden[i];
        float4 c = *(const float4*)&hidden[i + 4];
        v8s tv;
        tv[0] = (short)f2bf(a.x); tv[1] = (short)f2bf(a.y);
        tv[2] = (short)f2bf(a.z); tv[3] = (short)f2bf(a.w);
        tv[4] = (short)f2bf(c.x); tv[5] = (short)f2bf(c.y);
        tv[6] = (short)f2bf(c.z); tv[7] = (short)f2bf(c.w);
        *(v8s*)&hid_bf[i] = tv;
    } else if (b < 4608) {
        int idx = (b - 4096) * 256 + threadIdx.x;   // T*64 entries
        int tp = idx >> 6, i = idx & 63;
        float invf = exp2f(-(float)i * 0.31143075889569023f);  // log2(1e6)/64
        float f = (float)positions[tp] * invf;
        cosT[idx] = cosf(f);
        sinT[idx] = sinf(f);
    } else {
        int bx = b - 4608;                    // 96 x 64 tiles
        int n0 = (bx % 96) * 64, k0 = (bx / 96) * 64;
        transpose_tile64(w_qkv, wqkv_t, 4096, NQKV, n0, k0, tile, threadIdx.x);
    }
}

// ---------------- out-proj GEMM (kept 128^2 m97-structure): C = A @ Bt^T ----------------
__global__ __launch_bounds__(256) void gemm_bt_kernel(
    const u16* __restrict__ A, const u16* __restrict__ Bt, float* __restrict__ C, int N)
{
    __shared__ __align__(16) u16 smem[16896];
    u16* As = smem;
    u16* Bs = smem + 8192;
    int tid = threadIdx.x;
    int wave = tid >> 6, lane = tid & 63;
    int quad = lane >> 4, l15 = lane & 15;
    int lm = l15 & 7;
    int wm = wave >> 1, wn = wave & 1;
    int m0 = blockIdx.y * 128, n0 = blockIdx.x * 128;

    v4f acc[4][4];
    v4f z4 = {0.f, 0.f, 0.f, 0.f};
#pragma unroll
    for (int mi = 0; mi < 4; ++mi)
#pragma unroll
        for (int ni = 0; ni < 4; ++ni) acc[mi][ni] = z4;

    int rsub = lane >> 3;
    int cg = (lane & 7) ^ rsub;
    const u16* Ag = &A[(size_t)m0 * KD + cg * 8];
    const u16* Bg = &Bt[(size_t)n0 * KD + cg * 8];

    for (int k0 = 0; k0 < KD; k0 += 64) {
        __syncthreads();
#pragma unroll
        for (int c = 0; c < 4; ++c) {
            int ch = wave * 4 + c;
            int row = ch * 8 + rsub;
            gl2lds16(&Ag[(size_t)row * KD + k0], &As[ch * 512]);
            gl2lds16(&Bg[(size_t)row * KD + k0], &Bs[ch * 512]);
        }
        __syncthreads();
#pragma unroll
        for (int ks = 0; ks < 2; ++ks) {
            v8s af[4], bfr[4];
#pragma unroll
            for (int mi = 0; mi < 4; ++mi) {
                int ar = wm * 64 + mi * 16 + l15;
                af[mi] = *(const v8s*)&As[ar * 64 + ((((ks << 2) + quad) ^ lm) << 3)];
            }
#pragma unroll
            for (int ni = 0; ni < 4; ++ni) {
                int br = wn * 64 + ni * 16 + l15;
                bfr[ni] = *(const v8s*)&Bs[br * 64 + ((((ks << 2) + quad) ^ lm) << 3)];
            }
#pragma unroll
            for (int mi = 0; mi < 4; ++mi)
#pragma unroll
                for (int ni = 0; ni < 4; ++ni)
                    acc[mi][ni] = __builtin_amdgcn_mfma_f32_16x16x32_bf16(
                        af[mi], bfr[ni], acc[mi][ni], 0, 0, 0);
        }
    }
#pragma unroll
    for (int mi = 0; mi < 4; ++mi)
#pragma unroll
        for (int ni = 0; ni < 4; ++ni)
#pragma unroll
            for (int r = 0; r < 4; ++r)
                C[(size_t)(m0 + wm * 64 + mi * 16 + quad * 4 + r) * N +
                  (n0 + wn * 64 + ni * 16 + l15)] = acc[mi][ni][r];
}

// ---------------- QKV GEMM: 256^2 tile, 8-phase counted-vmcnt schedule ----------------
// 8 waves (2M x 4N); per-wave C = rows {qm*128+wm*64+mi*16}, cols {qn*128+wn*32+ni*16}.
// Quadrant phase order (qm,qn): (0,0)->(0,1)->(1,1)->(1,0); per phase 16 MFMA.
// Stage order (per tile t): p1: B0(t+1), p2: A0(t+2), p3: B1(t+2), p4: A1(t+2);
// one s_waitcnt vmcnt(6) per K-tile (3 half-tiles = 6 loads/thread in flight).
// NO sched_barrier(0): ds_reads are plain loads (compiler-tracked), and the wall
// blocked next-phase addr-VALU/load-issue from overlapping the MFMA cluster.
// LDS 128 KiB: buf b at b*32768 u16: A[256][64] @+0, B[256][64] @+16384 (granule-XOR swizzled).
__global__ __launch_bounds__(512, 2) void gemm256_qkv_kernel(
    const u16* __restrict__ A, const u16* __restrict__ Bt,
    const float* __restrict__ qw, const float* __restrict__ kw,
    const float* __restrict__ cosT, const float* __restrict__ sinT,
    u16* __restrict__ Qb, u16* __restrict__ Kb, u16* __restrict__ Vt)
{
    __shared__ __align__(16) char smem_raw[131072];
    u16* lds = (u16*)smem_raw;
    const int tid = threadIdx.x;
    const int wave = tid >> 6, lane = tid & 63;
    const int quad = lane >> 4, l15 = lane & 15, lm = l15 & 7;
    const int wm = wave >> 2, wn = wave & 3;
    const int m0 = blockIdx.y * 256, n0 = blockIdx.x * 256;

    v4f acc[2][2][4][2];
    v4f z4 = {0.f, 0.f, 0.f, 0.f};
#pragma unroll
    for (int a0 = 0; a0 < 2; ++a0)
#pragma unroll
        for (int b0 = 0; b0 < 2; ++b0)
#pragma unroll
            for (int mi = 0; mi < 4; ++mi)
#pragma unroll
                for (int ni = 0; ni < 2; ++ni) acc[a0][b0][mi][ni] = z4;

    const int rsub = lane >> 3;
    const int cg = (lane & 7) ^ rsub;           // pre-swizzled source granule
    const int ch0 = wave * 2;
    const int g0 = (quad ^ lm) << 3;            // u16 offset of ks=0 granule
    const int g1 = ((4 + quad) ^ lm) << 3;      // ks=1

    // hoisted staging row-base pointers (loop-invariant)
    const u16* AgR0 = &A[((size_t)m0 + (ch0 + 0) * 8 + rsub) * KD + cg * 8];
    const u16* AgR1 = &A[((size_t)m0 + (ch0 + 1) * 8 + rsub) * KD + cg * 8];
    const u16* BgR0 = &Bt[((size_t)n0 + (ch0 + 0) * 8 + rsub) * KD + cg * 8];
    const u16* BgR1 = &Bt[((size_t)n0 + (ch0 + 1) * 8 + rsub) * KD + cg * 8];

#define STAGE_A(tt, h) do { \
    int _b = ((tt) & 1) * 32768; \
    gl2lds16(AgR0 + (size_t)(h) * 128 * KD + (size_t)(tt) * 64, \
             &lds[_b + (h) * 8192 + (ch0 + 0) * 512]); \
    gl2lds16(AgR1 + (size_t)(h) * 128 * KD + (size_t)(tt) * 64, \
             &lds[_b + (h) * 8192 + (ch0 + 1) * 512]); \
  } while (0)
#define STAGE_B(tt, h) do { \
    int _b = ((tt) & 1) * 32768 + 16384; \
    gl2lds16(BgR0 + (size_t)(h) * 128 * KD + (size_t)(tt) * 64, \
             &lds[_b + (h) * 8192 + (ch0 + 0) * 512]); \
    gl2lds16(BgR1 + (size_t)(h) * 128 * KD + (size_t)(tt) * 64, \
             &lds[_b + (h) * 8192 + (ch0 + 1) * 512]); \
  } while (0)

    v8s af[4][2], bfr[2][2];

#define PHASE(QM, QN, RDA, RDB, STAGE_CODE, WAIT_CODE) do { \
    if (RDA) { \
      _Pragma("unroll") \
      for (int mi = 0; mi < 4; ++mi) { \
        const u16* ap = &lds[bo + ((QM) * 128 + wm * 64 + mi * 16 + l15) * 64]; \
        af[mi][0] = *(const v8s*)&ap[g0]; \
        af[mi][1] = *(const v8s*)&ap[g1]; \
      } } \
    if (RDB) { \
      _Pragma("unroll") \
      for (int ni = 0; ni < 2; ++ni) { \
        const u16* bp = &lds[bo + 16384 + ((QN) * 128 + wn * 32 + ni * 16 + l15) * 64]; \
        bfr[ni][0] = *(const v8s*)&bp[g0]; \
        bfr[ni][1] = *(const v8s*)&bp[g1]; \
      } } \
    STAGE_CODE; \
    __builtin_amdgcn_s_barrier(); \
    asm volatile("s_waitcnt lgkmcnt(0)" ::: "memory"); \
    __builtin_amdgcn_s_setprio(1); \
    _Pragma("unroll") \
    for (int mi = 0; mi < 4; ++mi) \
      _Pragma("unroll") \
      for (int ni = 0; ni < 2; ++ni) { \
        acc[QM][QN][mi][ni] = __builtin_amdgcn_mfma_f32_16x16x32_bf16( \
            af[mi][0], bfr[ni][0], acc[QM][QN][mi][ni], 0, 0, 0); \
        acc[QM][QN][mi][ni] = __builtin_amdgcn_mfma_f32_16x16x32_bf16( \
            af[mi][1], bfr[ni][1], acc[QM][QN][mi][ni], 0, 0, 0); \
      } \
    __builtin_amdgcn_s_setprio(0); \
    WAIT_CODE; \
    __builtin_amdgcn_s_barrier(); \
  } while (0)

    // prologue: tile 0 complete + 3 halves of tile 1; vmcnt(6) leaves those 3 in flight
    STAGE_A(0, 0); STAGE_B(0, 0); STAGE_B(0, 1); STAGE_A(0, 1);
    STAGE_A(1, 0); STAGE_B(1, 1); STAGE_A(1, 1);
    asm volatile("s_waitcnt vmcnt(6)" ::: "memory");
    __builtin_amdgcn_s_barrier();

#pragma unroll 2
    for (int t = 0; t < 64; ++t) {
        const int bo = (t & 1) * 32768;
        PHASE(0, 0, 1, 1, { if (t + 1 < 64) STAGE_B(t + 1, 0); }, {});
        PHASE(0, 1, 0, 1, { if (t + 2 < 64) STAGE_A(t + 2, 0); }, {});
        PHASE(1, 1, 1, 0, { if (t + 2 < 64) STAGE_B(t + 2, 1); }, {});
        PHASE(1, 0, 0, 1, { if (t + 2 < 64) STAGE_A(t + 2, 1); },
              { if (t + 2 < 64) { asm volatile("s_waitcnt vmcnt(6)" ::: "memory"); }
                else            { asm volatile("s_waitcnt vmcnt(0)" ::: "memory"); } });
    }
#undef PHASE
#undef STAGE_A
#undef STAGE_B

    // ---- fused epilogue: this block's 256 cols == two heads; process sequentially ----
    u16* Ct = lds;                 // [256][132] bf16, aliases staging LDS (dead now)
    const int t0q = blockIdx.y * 256;
#pragma unroll
    for (int hh = 0; hh < 2; ++hh) {
        __syncthreads();
#pragma unroll
        for (int qm = 0; qm < 2; ++qm)
#pragma unroll
            for (int mi = 0; mi < 4; ++mi)
#pragma unroll
                for (int ni = 0; ni < 2; ++ni)
#pragma unroll
                    for (int r = 0; r < 4; ++r)
                        Ct[(qm * 128 + wm * 64 + mi * 16 + quad * 4 + r) * 132 +
                           wn * 32 + ni * 16 + l15] = f2bf(acc[qm][hh][mi][ni][r]);
        __syncthreads();
        const int head = blockIdx.x * 2 + hh;   // 0..31 q, 32..39 k, 40..47 v
        if (head < 40) {
            if (tid < 256) {
                const int row = tid;
                const float* w = (head < 32) ? qw : kw;
                float ss = 0.f;
                for (int i = 0; i < 128; ++i) {
                    float x = bf2f(Ct[row * 132 + i]);
                    ss += x * x;
                }
                float rs = rsqrtf(ss * (1.0f / 128.0f) + 1e-6f);
                if (head < 32) rs *= QSCALE;   // fold 1/sqrt(HD)*log2e into Q
                const int ti = t0q + row;
                for (int i = 0; i < 64; ++i) {
                    float x1 = bf2f(Ct[row * 132 + i]) * rs * w[i];
                    float x2 = bf2f(Ct[row * 132 + 64 + i]) * rs * w[64 + i];
                    float c = cosT[ti * 64 + i], s = sinT[ti * 64 + i];
                    Ct[row * 132 + i]      = f2bf(x1 * c - x2 * s);
                    Ct[row * 132 + 64 + i] = f2bf(x2 * c + x1 * s);
                }
            }
            __syncthreads();
            u16* dst = (head < 32) ? &Qb[((size_t)head * TT + t0q) * HDM]
                                   : &Kb[((size_t)(head - 32) * TT + t0q) * HDM];
            for (int cix = tid; cix < 256 * 16; cix += 512) {
                int row = cix >> 4, part = (cix & 15) * 8;
                v8s tv;
#pragma unroll
                for (int j = 0; j < 8; ++j) tv[j] = (short)Ct[row * 132 + part + j];
                *(v8s*)&dst[row * HDM + part] = tv;
            }
        } else {
            // V head: write transposed Vt[kv][hd][t]
            const int kvh = head - 40;
            if (tid < 128) {
                const int hd = tid;
                for (int tb = 0; tb < 32; ++tb) {
                    v8s tv;
#pragma unroll
                    for (int j = 0; j < 8; ++j) tv[j] = (short)Ct[(tb * 8 + j) * 132 + hd];
                    *(v8s*)&Vt[((size_t)kvh * HDM + hd) * TT + t0q + tb * 8] = tv;
                }
            }
        }
    }
}

// ------- attn (blocks 0..1023) + w_o transpose backfill (1024..5119) -------
__global__ __launch_bounds__(256) void attn_plus_kernel(
    const u16* __restrict__ Qb, const u16* __restrict__ Kb,
    const u16* __restrict__ Vt, u16* __restrict__ Ob,
    const float* __restrict__ w_o, u16* __restrict__ wo_t)
{
    __shared__ __align__(16) char smem_raw[40960];
    int tid = threadIdx.x;
    if (blockIdx.x >= 1024) {
        int bx = blockIdx.x - 1024;           // 64 x 64 tiles
        int n0 = (bx & 63) * 64, k0 = (bx >> 6) * 64;
        transpose_tile64(w_o, wo_t, 4096, 4096, n0, k0, (float*)smem_raw, tid);
        return;
    }
    u16* Kl = (u16*)smem_raw;                  // [s][hd] swizzled, 16384 B
    u16* Vl = (u16*)(smem_raw + 16384);        // [hd][s] swizzled, 16384 B
    u16* Pl = (u16*)(smem_raw + 32768);        // per-wave P, swizzled, 8192 B
    int wave = tid >> 6, lane = tid & 63;
    int quad = lane >> 4, l15 = lane & 15;
    int idx = blockIdx.x;
    int h = idx & 31;
    int qb = 31 - (idx >> 5);        // longest blocks dispatch first
    int kv = h >> 2;                 // H/KV = 4
    int q0 = qb * 64;
    int lm = l15 & 7;                // swizzle mask for this lane's row group

    v8s qf[4];
    {
        const u16* qr = &Qb[((size_t)h * TT + q0 + wave * 16 + l15) * HDM];
#pragma unroll
        for (int ks = 0; ks < 4; ++ks) qf[ks] = *(const v8s*)&qr[ks * 32 + quad * 8];
    }

    v4f z4 = {0.f, 0.f, 0.f, 0.f};
    v4f of[8];
#pragma unroll
    for (int i = 0; i < 8; ++i) of[i] = z4;
    float lsum[4];
#pragma unroll
    for (int r = 0; r < 4; ++r) lsum[r] = 0.f;
    u16* Pw = &Pl[wave * 1024];

    for (int s0 = 0; s0 <= q0; s0 += 64) {
        __syncthreads();
#pragma unroll
        for (int c = 0; c < 4; ++c) {
            int ch = wave * 4 + c;
            int rk = ch * 4 + (lane >> 4);              // Kl row (s-local)
            int ck = (lane & 15) ^ (rk & 7);            // logical chunk to fetch
            gl2lds16(&Kb[((size_t)kv * TT + s0 + rk) * HDM + ck * 8], &Kl[ch * 512]);
            int rv = ch * 8 + (lane >> 3);              // Vl row (hd)
            int cv = (lane & 7) ^ (rv & 7);
            gl2lds16(&Vt[((size_t)kv * HDM + rv) * TT + s0 + cv * 8], &Vl[ch * 512]);
        }
        __syncthreads();
        // S = Q @ K^T  (C-layout: row=quad*4+r, col=l15 within n-tile)
        v4f sf[4];
#pragma unroll
        for (int nt = 0; nt < 4; ++nt) {
            v4f cacc = z4;
#pragma unroll
            for (int ks = 0; ks < 4; ++ks)
                cacc = __builtin_amdgcn_mfma_f32_16x16x32_bf16(
                    qf[ks],
                    *(const v8s*)&Kl[(nt * 16 + l15) * 128 + (((ks * 4 + quad) ^ lm) << 3)],
                    cacc, 0, 0, 0);
            sf[nt] = cacc;
        }
        if (s0 == q0) {   // only the diagonal tile needs the causal mask
#pragma unroll
            for (int nt = 0; nt < 4; ++nt) {
                int sg = s0 + nt * 16 + l15;
#pragma unroll
                for (int r = 0; r < 4; ++r) {
                    int qg = q0 + wave * 16 + quad * 4 + r;
                    if (sg > qg) sf[nt][r] = -3.0e38f;
                }
            }
        }
        // fixed-max softmax: p = exp2(S*log2e - 12*log2e); masked -> exp2(-inf)=0
#pragma unroll
        for (int nt = 0; nt < 4; ++nt)
#pragma unroll
            for (int r = 0; r < 4; ++r) {
                float p = exp2f(sf[nt][r] - EOFF);
                sf[nt][r] = p;
                lsum[r] += p;
            }
        // P: C-layout -> swizzled LDS (A-layout source for PV)
#pragma unroll
        for (int nt = 0; nt < 4; ++nt)
#pragma unroll
            for (int r = 0; r < 4; ++r) {
                int row = quad * 4 + r;
                int pch = ((nt << 1) + (l15 >> 3)) ^ (row & 7);
                Pw[row * 64 + pch * 8 + (l15 & 7)] = f2bf(sf[nt][r]);
            }
        // O += P @ V  (no rescale needed with fixed max)
#pragma unroll
        for (int sub = 0; sub < 2; ++sub) {
            v8s pa = *(const v8s*)&Pw[l15 * 64 + ((((sub << 2) + quad) ^ lm) << 3)];
#pragma unroll
            for (int nt = 0; nt < 8; ++nt)
                of[nt] = __builtin_amdgcn_mfma_f32_16x16x32_bf16(
                    pa,
                    *(const v8s*)&Vl[(nt * 16 + l15) * 64 + ((((sub << 2) + quad) ^ lm) << 3)],
                    of[nt], 0, 0, 0);
        }
    }
    // single end-of-kernel l reduction across the 16 col-lanes (same quad group)
#pragma unroll
    for (int off = 1; off < 16; off <<= 1)
#pragma unroll
        for (int r = 0; r < 4; ++r) lsum[r] += __shfl_xor(lsum[r], off, 64);
    float invl[4];
#pragma unroll
    for (int r = 0; r < 4; ++r) invl[r] = 1.0f / lsum[r];
#pragma unroll
    for (int nt = 0; nt < 8; ++nt)
#pragma unroll
        for (int r = 0; r < 4; ++r)
            Ob[(size_t)(q0 + wave * 16 + quad * 4 + r) * (NH * HDM) + h * HDM + nt * 16 + l15] =
                f2bf(of[nt][r] * invl[r]);
}

extern "C" void kernel_launch(void* const* d_in, const int* in_sizes, int n_in,
                              void* d_out, int out_size, void* d_ws, size_t ws_size,
                              hipStream_t stream)
{
    (void)in_sizes; (void)n_in; (void)out_size; (void)ws_size;
    const int*   positions = (const int*)d_in[0];
    const float* hidden    = (const float*)d_in[1];
    const float* w_qkv     = (const float*)d_in[2];
    const float* q_norm_w  = (const float*)d_in[3];
    const float* k_norm_w  = (const float*)d_in[4];
    const float* w_o       = (const float*)d_in[5];
    float* out = (float*)d_out;
    char* ws = (char*)d_ws;
    char* ob = (char*)d_out;

    // ---- d_ws layout (peak = 64 MiB exactly) ----
    u16* hid_bf = (u16*)(ws + 0);                 // [2048][4096] bf16      16 MiB
    u16* attnO  = (u16*)(ws + 0);                 // aliases hid_bf (dead after QKV GEMM)
    u16* wqkv_t = (u16*)(ws + (size_t)16777216);  // [6144][4096] bf16      50.33 MiB (ends at 64 MiB)
    u16* wo_t   = (u16*)(ws + (size_t)16777216);  // [4096][4096] bf16, overwrites wqkv_t after QKV GEMM

    // ---- d_out-hosted scratch (26.2 MiB <= 32 MiB; all dead before final GEMM) ----
    u16*   Qb   = (u16*)(ob + 0);                 // [32][2048][128]     16 MiB
    u16*   Kb   = (u16*)(ob + (size_t)16777216);  // [8][2048][128]      4 MiB
    u16*   Vt   = (u16*)(ob + (size_t)20971520);  // [8][128][2048]      4 MiB
    float* cosT = (float*)(ob + (size_t)25165824);// [2048][64]          0.5 MiB
    float* sinT = (float*)(ob + (size_t)25690112);// [2048][64]          0.5 MiB

    // hidden cast + RoPE tables + w_qkv transpose, one launch
    prep_all_kernel<<<10752, 256, 0, stream>>>(hidden, hid_bf, positions, cosT, sinT,
                                               w_qkv, wqkv_t);

    // fused QKV GEMM: 256^2 8-phase schedule (192 blocks, 1/CU)
    gemm256_qkv_kernel<<<dim3(24, 8), 512, 0, stream>>>(
        hid_bf, wqkv_t, q_norm_w, k_norm_w, cosT, sinT, Qb, Kb, Vt);

    // attention (1024 blocks) + w_o transpose backfill (4096 blocks), one launch
    attn_plus_kernel<<<5120, 256, 0, stream>>>(Qb, Kb, Vt, attnO, w_o, wo_t);

    // out-proj GEMM writes fp32 over all of d_out
    gemm_bt_kernel<<<dim3(32, 16), 256, 0, stream>>>(attnO, wo_t, out, 4096);
}

// Round 5
// 456.919 us; speedup vs baseline: 1.0539x; 1.0539x over previous
//
#include <hip/hip_runtime.h>

#define TT   2048
#define DD   4096
#define NH   32
#define NKVH 8
#define HDM  128
#define KD   4096
#define NQKV 6144

typedef unsigned short u16;
typedef short v8s __attribute__((ext_vector_type(8)));
typedef float v4f __attribute__((ext_vector_type(4)));

// Q pre-scale: 1/sqrt(128) * log2(e)  (log2e folded so attn uses bare exp2)
#define QSCALE 0.12751744547734565f
// fixed softmax max: 12 * log2(e). Valid because |S| <= |q||k|/sqrt(128) = 11.32
#define EOFF   17.312340490667562f

__device__ __forceinline__ u16 f2bf(float f) {
    unsigned u = __builtin_bit_cast(unsigned, f);
    u += 0x7fffu + ((u >> 16) & 1u);   // round-to-nearest-even
    return (u16)(u >> 16);
}
__device__ __forceinline__ float bf2f(u16 h) {
    return __builtin_bit_cast(float, ((unsigned)h) << 16);
}
__device__ __forceinline__ void gl2lds16(const void* g, void* l) {
    // async global->LDS, 16B/lane; LDS dest = wave-uniform base + lane*16
    using gv = const __attribute__((address_space(1))) void;
    using lv = __attribute__((address_space(3))) void;
    __builtin_amdgcn_global_load_lds((gv*)g, (lv*)l, 16, 0, 0);
}

// -------- 64x64 transpose+cast tile: out[n][k] = bf16(in[k][n]) --------
__device__ __forceinline__ void transpose_tile64(const float* __restrict__ in,
                                                 u16* __restrict__ out,
                                                 int K, int N, int n0, int k0,
                                                 float* tile, int t) {
    int rc = t >> 4, cc = (t & 15) * 4;
#pragma unroll
    for (int p = 0; p < 4; ++p) {
        int k = p * 16 + rc;
        float4 v = *(const float4*)&in[(size_t)(k0 + k) * N + n0 + cc];
        tile[k * 65 + cc] = v.x; tile[k * 65 + cc + 1] = v.y;
        tile[k * 65 + cc + 2] = v.z; tile[k * 65 + cc + 3] = v.w;
    }
    __syncthreads();
    int rn = t >> 3, ck = (t & 7) * 8;
#pragma unroll
    for (int p = 0; p < 2; ++p) {
        int n = p * 32 + rn;
        v8s tv;
#pragma unroll
        for (int j = 0; j < 8; ++j) tv[j] = (short)f2bf(tile[(ck + j) * 65 + n]);
        *(v8s*)&out[(size_t)(n0 + n) * K + k0 + ck] = tv;
    }
}

// ------- prep_all: hidden cast (0..4095) + RoPE tab (4096..4607) + w_qkv^T (4608..10751) -------
__global__ __launch_bounds__(256) void prep_all_kernel(const float* __restrict__ hidden,
                                                       u16* __restrict__ hid_bf,
                                                       const int* __restrict__ positions,
                                                       float* __restrict__ cosT,
                                                       float* __restrict__ sinT,
                                                       const float* __restrict__ w_qkv,
                                                       u16* __restrict__ wqkv_t) {
    __shared__ float tile[64 * 65];
    int b = blockIdx.x;
    if (b < 4096) {
        size_t i = ((size_t)b * 256 + threadIdx.x) * 8;
        float4 a = *(const float4*)&hidden[i];
        float4 c = *(const float4*)&hidden[i + 4];
        v8s tv;
        tv[0] = (short)f2bf(a.x); tv[1] = (short)f2bf(a.y);
        tv[2] = (short)f2bf(a.z); tv[3] = (short)f2bf(a.w);
        tv[4] = (short)f2bf(c.x); tv[5] = (short)f2bf(c.y);
        tv[6] = (short)f2bf(c.z); tv[7] = (short)f2bf(c.w);
        *(v8s*)&hid_bf[i] = tv;
    } else if (b < 4608) {
        int idx = (b - 4096) * 256 + threadIdx.x;   // T*64 entries
        int tp = idx >> 6, i = idx & 63;
        float invf = exp2f(-(float)i * 0.31143075889569023f);  // log2(1e6)/64
        float f = (float)positions[tp] * invf;
        cosT[idx] = cosf(f);
        sinT[idx] = sinf(f);
    } else {
        int bx = b - 4608;                    // 96 x 64 tiles
        int n0 = (bx % 96) * 64, k0 = (bx / 96) * 64;
        transpose_tile64(w_qkv, wqkv_t, 4096, NQKV, n0, k0, tile, threadIdx.x);
    }
}

// ---------------- out-proj GEMM (kept 128^2 m97-structure): C = A @ Bt^T ----------------
__global__ __launch_bounds__(256) void gemm_bt_kernel(
    const u16* __restrict__ A, const u16* __restrict__ Bt, float* __restrict__ C, int N)
{
    __shared__ __align__(16) u16 smem[16896];
    u16* As = smem;
    u16* Bs = smem + 8192;
    int tid = threadIdx.x;
    int wave = tid >> 6, lane = tid & 63;
    int quad = lane >> 4, l15 = lane & 15;
    int lm = l15 & 7;
    int wm = wave >> 1, wn = wave & 1;
    int m0 = blockIdx.y * 128, n0 = blockIdx.x * 128;

    v4f acc[4][4];
    v4f z4 = {0.f, 0.f, 0.f, 0.f};
#pragma unroll
    for (int mi = 0; mi < 4; ++mi)
#pragma unroll
        for (int ni = 0; ni < 4; ++ni) acc[mi][ni] = z4;

    int rsub = lane >> 3;
    int cg = (lane & 7) ^ rsub;
    const u16* Ag = &A[(size_t)m0 * KD + cg * 8];
    const u16* Bg = &Bt[(size_t)n0 * KD + cg * 8];

    for (int k0 = 0; k0 < KD; k0 += 64) {
        __syncthreads();
#pragma unroll
        for (int c = 0; c < 4; ++c) {
            int ch = wave * 4 + c;
            int row = ch * 8 + rsub;
            gl2lds16(&Ag[(size_t)row * KD + k0], &As[ch * 512]);
            gl2lds16(&Bg[(size_t)row * KD + k0], &Bs[ch * 512]);
        }
        __syncthreads();
#pragma unroll
        for (int ks = 0; ks < 2; ++ks) {
            v8s af[4], bfr[4];
#pragma unroll
            for (int mi = 0; mi < 4; ++mi) {
                int ar = wm * 64 + mi * 16 + l15;
                af[mi] = *(const v8s*)&As[ar * 64 + ((((ks << 2) + quad) ^ lm) << 3)];
            }
#pragma unroll
            for (int ni = 0; ni < 4; ++ni) {
                int br = wn * 64 + ni * 16 + l15;
                bfr[ni] = *(const v8s*)&Bs[br * 64 + ((((ks << 2) + quad) ^ lm) << 3)];
            }
#pragma unroll
            for (int mi = 0; mi < 4; ++mi)
#pragma unroll
                for (int ni = 0; ni < 4; ++ni)
                    acc[mi][ni] = __builtin_amdgcn_mfma_f32_16x16x32_bf16(
                        af[mi], bfr[ni], acc[mi][ni], 0, 0, 0);
        }
    }
#pragma unroll
    for (int mi = 0; mi < 4; ++mi)
#pragma unroll
        for (int ni = 0; ni < 4; ++ni)
#pragma unroll
            for (int r = 0; r < 4; ++r)
                C[(size_t)(m0 + wm * 64 + mi * 16 + quad * 4 + r) * N +
                  (n0 + wn * 64 + ni * 16 + l15)] = acc[mi][ni][r];
}

// ---------------- QKV GEMM: 128x384 tile, 4-phase schedule, 256 blocks (100% fill) ----------------
// 8 waves (2M x 4N); per-wave C = rows {wm*64+mi*16} (mi<4), cols {wn*96+nh*48+ni*16} (ni<3).
// Phases per K-tile: (ks0,nh0)(ks0,nh1)(ks1,nh0)(ks1,nh1); 12 MFMA each; af reused across nh.
// Staging: 4 halves of 128 rows (A, B0, B1, B2). All halves of tile t+1 issued at p1-p3 of
// tile t; single vmcnt(0) at p4 sits >=1100cy after last issue -> latency covered, no drain.
// LDS 128 KiB: buf b at b*32768 u16: A[128][64] @+0 (8192), B[384][64] @+8192 (24576).
// Granule-XOR swizzle as before (source granule cg=(lane&7)^rsub; read granule (ks*4+quad)^lm).
__global__ __launch_bounds__(512, 2) void gemm_qkv384_kernel(
    const u16* __restrict__ A, const u16* __restrict__ Bt,
    const float* __restrict__ qw, const float* __restrict__ kw,
    const float* __restrict__ cosT, const float* __restrict__ sinT,
    u16* __restrict__ Qb, u16* __restrict__ Kb, u16* __restrict__ Vt)
{
    __shared__ __align__(16) char smem_raw[131072];
    u16* lds = (u16*)smem_raw;
    const int tid = threadIdx.x;
    const int wave = tid >> 6, lane = tid & 63;
    const int quad = lane >> 4, l15 = lane & 15, lm = l15 & 7;
    const int wm = wave >> 2, wn = wave & 3;        // 2M x 4N
    const int m0 = blockIdx.y * 128, n0 = blockIdx.x * 384;

    v4f acc[2][4][3];
    v4f z4 = {0.f, 0.f, 0.f, 0.f};
#pragma unroll
    for (int nh = 0; nh < 2; ++nh)
#pragma unroll
        for (int mi = 0; mi < 4; ++mi)
#pragma unroll
            for (int ni = 0; ni < 3; ++ni) acc[nh][mi][ni] = z4;

    const int rsub = lane >> 3;
    const int cg = (lane & 7) ^ rsub;           // pre-swizzled source granule
    const int ch0 = wave * 2;
    const int g0 = (quad ^ lm) << 3;            // u16 offset of ks=0 granule
    const int g1 = ((4 + quad) ^ lm) << 3;      // ks=1

    // hoisted staging row-base pointers (loop-invariant)
    const u16* AgR0 = &A[((size_t)m0 + (ch0 + 0) * 8 + rsub) * KD + cg * 8];
    const u16* AgR1 = &A[((size_t)m0 + (ch0 + 1) * 8 + rsub) * KD + cg * 8];
    const u16* BgR0 = &Bt[((size_t)n0 + (ch0 + 0) * 8 + rsub) * KD + cg * 8];
    const u16* BgR1 = &Bt[((size_t)n0 + (ch0 + 1) * 8 + rsub) * KD + cg * 8];

#define STAGE_AH(tt) do { \
    int _b = ((tt) & 1) * 32768; \
    gl2lds16(AgR0 + (size_t)(tt) * 64, &lds[_b + (ch0 + 0) * 512]); \
    gl2lds16(AgR1 + (size_t)(tt) * 64, &lds[_b + (ch0 + 1) * 512]); \
  } while (0)
#define STAGE_BH(tt, h) do { \
    int _b = ((tt) & 1) * 32768 + 8192; \
    gl2lds16(BgR0 + (size_t)(h) * 128 * KD + (size_t)(tt) * 64, \
             &lds[_b + (h) * 8192 + (ch0 + 0) * 512]); \
    gl2lds16(BgR1 + (size_t)(h) * 128 * KD + (size_t)(tt) * 64, \
             &lds[_b + (h) * 8192 + (ch0 + 1) * 512]); \
  } while (0)

    v8s af[4], bfr[3];

#define PHASEX(BO, G, NHI, RDA, STAGE_CODE, WAIT_CODE) do { \
    if (RDA) { \
      _Pragma("unroll") \
      for (int mi = 0; mi < 4; ++mi) \
        af[mi] = *(const v8s*)&lds[(BO) + (wm * 64 + mi * 16 + l15) * 64 + (G)]; \
    } \
    _Pragma("unroll") \
    for (int ni = 0; ni < 3; ++ni) \
      bfr[ni] = *(const v8s*)&lds[(BO) + 8192 + \
                   (wn * 96 + (NHI) * 48 + ni * 16 + l15) * 64 + (G)]; \
    STAGE_CODE; \
    __builtin_amdgcn_s_barrier(); \
    asm volatile("s_waitcnt lgkmcnt(0)" ::: "memory"); \
    __builtin_amdgcn_s_setprio(1); \
    _Pragma("unroll") \
    for (int mi = 0; mi < 4; ++mi) \
      _Pragma("unroll") \
      for (int ni = 0; ni < 3; ++ni) \
        acc[NHI][mi][ni] = __builtin_amdgcn_mfma_f32_16x16x32_bf16( \
            af[mi], bfr[ni], acc[NHI][mi][ni], 0, 0, 0); \
    __builtin_amdgcn_s_setprio(0); \
    WAIT_CODE; \
    __builtin_amdgcn_s_barrier(); \
  } while (0)

#define VM0 asm volatile("s_waitcnt vmcnt(0)" ::: "memory")

#define TILE_MAIN(BO, TT1) do { \
    PHASEX(BO, g0, 0, 1, { STAGE_AH(TT1); STAGE_BH(TT1, 0); }, {}); \
    PHASEX(BO, g0, 1, 0, { STAGE_BH(TT1, 1); }, {}); \
    PHASEX(BO, g1, 0, 1, { STAGE_BH(TT1, 2); }, {}); \
    PHASEX(BO, g1, 1, 0, {}, { VM0; }); \
  } while (0)

    // prologue: tile 0 all four halves, then drain
    STAGE_AH(0); STAGE_BH(0, 0); STAGE_BH(0, 1); STAGE_BH(0, 2);
    VM0;
    __builtin_amdgcn_s_barrier();

    // main loop: tiles 0..61 (stages t+1 = 1..62); even trip count for unroll 2
#pragma unroll 2
    for (int t = 0; t < 62; ++t) {
        const int bo = (t & 1) * 32768;
        TILE_MAIN(bo, t + 1);
    }
    // tile 62 (buf 0): stages tile 63
    TILE_MAIN(0, 63);
    // tile 63 (buf 1): pure compute
    PHASEX(32768, g0, 0, 1, {}, {});
    PHASEX(32768, g0, 1, 0, {}, {});
    PHASEX(32768, g1, 0, 1, {}, {});
    PHASEX(32768, g1, 1, 0, {}, {});
#undef TILE_MAIN
#undef PHASEX
#undef STAGE_AH
#undef STAGE_BH
#undef VM0

    // ---- fused epilogue: this block's 384 cols == three heads ----
    u16* Ct = lds;                 // [128][392] bf16, aliases staging LDS (dead now)
    const int t0q = blockIdx.y * 128;
    __syncthreads();
#pragma unroll
    for (int nh = 0; nh < 2; ++nh)
#pragma unroll
        for (int mi = 0; mi < 4; ++mi)
#pragma unroll
            for (int ni = 0; ni < 3; ++ni)
#pragma unroll
                for (int r = 0; r < 4; ++r)
                    Ct[(wm * 64 + mi * 16 + quad * 4 + r) * 392 +
                       wn * 96 + nh * 48 + ni * 16 + l15] = f2bf(acc[nh][mi][ni][r]);
    __syncthreads();
    // RMSNorm + RoPE for Q/K heads (rows 0..127 x heads 0..2 = 384 tasks)
    if (tid < 384) {
        const int row = tid & 127, hh = tid >> 7;
        const int head = blockIdx.x * 3 + hh;   // 0..31 q, 32..39 k, 40..47 v
        if (head < 40) {
            const float* w = (head < 32) ? qw : kw;
            float ss = 0.f;
            for (int i = 0; i < 128; ++i) {
                float x = bf2f(Ct[row * 392 + hh * 128 + i]);
                ss += x * x;
            }
            float rs = rsqrtf(ss * (1.0f / 128.0f) + 1e-6f);
            if (head < 32) rs *= QSCALE;   // fold 1/sqrt(HD)*log2e into Q
            const int ti = t0q + row;
            for (int i = 0; i < 64; ++i) {
                float x1 = bf2f(Ct[row * 392 + hh * 128 + i]) * rs * w[i];
                float x2 = bf2f(Ct[row * 392 + hh * 128 + 64 + i]) * rs * w[64 + i];
                float c = cosT[ti * 64 + i], s = sinT[ti * 64 + i];
                Ct[row * 392 + hh * 128 + i]      = f2bf(x1 * c - x2 * s);
                Ct[row * 392 + hh * 128 + 64 + i] = f2bf(x2 * c + x1 * s);
            }
        }
    }
    __syncthreads();
    // store phase: per head, all 512 threads
#pragma unroll
    for (int hh = 0; hh < 3; ++hh) {
        const int head = blockIdx.x * 3 + hh;
        if (head < 40) {
            u16* dst = (head < 32) ? &Qb[((size_t)head * TT + t0q) * HDM]
                                   : &Kb[((size_t)(head - 32) * TT + t0q) * HDM];
            for (int cix = tid; cix < 128 * 16; cix += 512) {
                int row = cix >> 4, part = (cix & 15) * 8;
                v8s tv;
#pragma unroll
                for (int j = 0; j < 8; ++j) tv[j] = (short)Ct[row * 392 + hh * 128 + part + j];
                *(v8s*)&dst[row * HDM + part] = tv;
            }
        } else {
            // V head: write transposed Vt[kv][hd][t]
            const int kvh = head - 40;
            for (int cix = tid; cix < 128 * 16; cix += 512) {
                int hd = cix >> 4, tb = cix & 15;
                v8s tv;
#pragma unroll
                for (int j = 0; j < 8; ++j) tv[j] = (short)Ct[(tb * 8 + j) * 392 + hh * 128 + hd];
                *(v8s*)&Vt[((size_t)kvh * HDM + hd) * TT + t0q + tb * 8] = tv;
            }
        }
    }
}

// ------- attn (blocks 0..1023) + w_o transpose backfill (1024..5119) -------
__global__ __launch_bounds__(256) void attn_plus_kernel(
    const u16* __restrict__ Qb, const u16* __restrict__ Kb,
    const u16* __restrict__ Vt, u16* __restrict__ Ob,
    const float* __restrict__ w_o, u16* __restrict__ wo_t)
{
    __shared__ __align__(16) char smem_raw[40960];
    int tid = threadIdx.x;
    if (blockIdx.x >= 1024) {
        int bx = blockIdx.x - 1024;           // 64 x 64 tiles
        int n0 = (bx & 63) * 64, k0 = (bx >> 6) * 64;
        transpose_tile64(w_o, wo_t, 4096, 4096, n0, k0, (float*)smem_raw, tid);
        return;
    }
    u16* Kl = (u16*)smem_raw;                  // [s][hd] swizzled, 16384 B
    u16* Vl = (u16*)(smem_raw + 16384);        // [hd][s] swizzled, 16384 B
    u16* Pl = (u16*)(smem_raw + 32768);        // per-wave P, swizzled, 8192 B
    int wave = tid >> 6, lane = tid & 63;
    int quad = lane >> 4, l15 = lane & 15;
    int idx = blockIdx.x;
    int h = idx & 31;
    int qb = 31 - (idx >> 5);        // longest blocks dispatch first
    int kv = h >> 2;                 // H/KV = 4
    int q0 = qb * 64;
    int lm = l15 & 7;                // swizzle mask for this lane's row group

    v8s qf[4];
    {
        const u16* qr = &Qb[((size_t)h * TT + q0 + wave * 16 + l15) * HDM];
#pragma unroll
        for (int ks = 0; ks < 4; ++ks) qf[ks] = *(const v8s*)&qr[ks * 32 + quad * 8];
    }

    v4f z4 = {0.f, 0.f, 0.f, 0.f};
    v4f of[8];
#pragma unroll
    for (int i = 0; i < 8; ++i) of[i] = z4;
    float lsum[4];
#pragma unroll
    for (int r = 0; r < 4; ++r) lsum[r] = 0.f;
    u16* Pw = &Pl[wave * 1024];

    for (int s0 = 0; s0 <= q0; s0 += 64) {
        __syncthreads();
#pragma unroll
        for (int c = 0; c < 4; ++c) {
            int ch = wave * 4 + c;
            int rk = ch * 4 + (lane >> 4);              // Kl row (s-local)
            int ck = (lane & 15) ^ (rk & 7);            // logical chunk to fetch
            gl2lds16(&Kb[((size_t)kv * TT + s0 + rk) * HDM + ck * 8], &Kl[ch * 512]);
            int rv = ch * 8 + (lane >> 3);              // Vl row (hd)
            int cv = (lane & 7) ^ (rv & 7);
            gl2lds16(&Vt[((size_t)kv * HDM + rv) * TT + s0 + cv * 8], &Vl[ch * 512]);
        }
        __syncthreads();
        // S = Q @ K^T  (C-layout: row=quad*4+r, col=l15 within n-tile)
        v4f sf[4];
#pragma unroll
        for (int nt = 0; nt < 4; ++nt) {
            v4f cacc = z4;
#pragma unroll
            for (int ks = 0; ks < 4; ++ks)
                cacc = __builtin_amdgcn_mfma_f32_16x16x32_bf16(
                    qf[ks],
                    *(const v8s*)&Kl[(nt * 16 + l15) * 128 + (((ks * 4 + quad) ^ lm) << 3)],
                    cacc, 0, 0, 0);
            sf[nt] = cacc;
        }
        if (s0 == q0) {   // only the diagonal tile needs the causal mask
#pragma unroll
            for (int nt = 0; nt < 4; ++nt) {
                int sg = s0 + nt * 16 + l15;
#pragma unroll
                for (int r = 0; r < 4; ++r) {
                    int qg = q0 + wave * 16 + quad * 4 + r;
                    if (sg > qg) sf[nt][r] = -3.0e38f;
                }
            }
        }
        // fixed-max softmax: p = exp2(S*log2e - 12*log2e); masked -> exp2(-inf)=0
#pragma unroll
        for (int nt = 0; nt < 4; ++nt)
#pragma unroll
            for (int r = 0; r < 4; ++r) {
                float p = exp2f(sf[nt][r] - EOFF);
                sf[nt][r] = p;
                lsum[r] += p;
            }
        // P: C-layout -> swizzled LDS (A-layout source for PV)
#pragma unroll
        for (int nt = 0; nt < 4; ++nt)
#pragma unroll
            for (int r = 0; r < 4; ++r) {
                int row = quad * 4 + r;
                int pch = ((nt << 1) + (l15 >> 3)) ^ (row & 7);
                Pw[row * 64 + pch * 8 + (l15 & 7)] = f2bf(sf[nt][r]);
            }
        // O += P @ V  (no rescale needed with fixed max)
#pragma unroll
        for (int sub = 0; sub < 2; ++sub) {
            v8s pa = *(const v8s*)&Pw[l15 * 64 + ((((sub << 2) + quad) ^ lm) << 3)];
#pragma unroll
            for (int nt = 0; nt < 8; ++nt)
                of[nt] = __builtin_amdgcn_mfma_f32_16x16x32_bf16(
                    pa,
                    *(const v8s*)&Vl[(nt * 16 + l15) * 64 + ((((sub << 2) + quad) ^ lm) << 3)],
                    of[nt], 0, 0, 0);
        }
    }
    // single end-of-kernel l reduction across the 16 col-lanes (same quad group)
#pragma unroll
    for (int off = 1; off < 16; off <<= 1)
#pragma unroll
        for (int r = 0; r < 4; ++r) lsum[r] += __shfl_xor(lsum[r], off, 64);
    float invl[4];
#pragma unroll
    for (int r = 0; r < 4; ++r) invl[r] = 1.0f / lsum[r];
#pragma unroll
    for (int nt = 0; nt < 8; ++nt)
#pragma unroll
        for (int r = 0; r < 4; ++r)
            Ob[(size_t)(q0 + wave * 16 + quad * 4 + r) * (NH * HDM) + h * HDM + nt * 16 + l15] =
                f2bf(of[nt][r] * invl[r]);
}

extern "C" void kernel_launch(void* const* d_in, const int* in_sizes, int n_in,
                              void* d_out, int out_size, void* d_ws, size_t ws_size,
                              hipStream_t stream)
{
    (void)in_sizes; (void)n_in; (void)out_size; (void)ws_size;
    const int*   positions = (const int*)d_in[0];
    const float* hidden    = (const float*)d_in[1];
    const float* w_qkv     = (const float*)d_in[2];
    const float* q_norm_w  = (const float*)d_in[3];
    const float* k_norm_w  = (const float*)d_in[4];
    const float* w_o       = (const float*)d_in[5];
    float* out = (float*)d_out;
    char* ws = (char*)d_ws;
    char* ob = (char*)d_out;

    // ---- d_ws layout (peak = 64 MiB exactly) ----
    u16* hid_bf = (u16*)(ws + 0);                 // [2048][4096] bf16      16 MiB
    u16* attnO  = (u16*)(ws + 0);                 // aliases hid_bf (dead after QKV GEMM)
    u16* wqkv_t = (u16*)(ws + (size_t)16777216);  // [6144][4096] bf16      50.33 MiB (ends at 64 MiB)
    u16* wo_t   = (u16*)(ws + (size_t)16777216);  // [4096][4096] bf16, overwrites wqkv_t after QKV GEMM

    // ---- d_out-hosted scratch (26.2 MiB <= 32 MiB; all dead before final GEMM) ----
    u16*   Qb   = (u16*)(ob + 0);                 // [32][2048][128]     16 MiB
    u16*   Kb   = (u16*)(ob + (size_t)16777216);  // [8][2048][128]      4 MiB
    u16*   Vt   = (u16*)(ob + (size_t)20971520);  // [8][128][2048]      4 MiB
    float* cosT = (float*)(ob + (size_t)25165824);// [2048][64]          0.5 MiB
    float* sinT = (float*)(ob + (size_t)25690112);// [2048][64]          0.5 MiB

    // hidden cast + RoPE tables + w_qkv transpose, one launch
    prep_all_kernel<<<10752, 256, 0, stream>>>(hidden, hid_bf, positions, cosT, sinT,
                                               w_qkv, wqkv_t);

    // fused QKV GEMM: 128x384 tiles, 256 blocks (100% CU fill)
    gemm_qkv384_kernel<<<dim3(16, 16), 512, 0, stream>>>(
        hid_bf, wqkv_t, q_norm_w, k_norm_w, cosT, sinT, Qb, Kb, Vt);

    // attention (1024 blocks) + w_o transpose backfill (4096 blocks), one launch
    attn_plus_kernel<<<5120, 256, 0, stream>>>(Qb, Kb, Vt, attnO, w_o, wo_t);

    // out-proj GEMM writes fp32 over all of d_out
    gemm_bt_kernel<<<dim3(32, 16), 256, 0, stream>>>(attnO, wo_t, out, 4096);
}

// Round 6
// 451.316 us; speedup vs baseline: 1.0670x; 1.0124x over previous
//
#include <hip/hip_runtime.h>

#define TT   2048
#define DD   4096
#define NH   32
#define NKVH 8
#define HDM  128
#define KD   4096
#define NQKV 6144

typedef unsigned short u16;
typedef short v8s __attribute__((ext_vector_type(8)));
typedef float v4f __attribute__((ext_vector_type(4)));

// Q pre-scale: 1/sqrt(128) * log2(e)  (log2e folded so attn uses bare exp2)
#define QSCALE 0.12751744547734565f
// fixed softmax max: 12 * log2(e). Valid because |S| <= |q||k|/sqrt(128) = 11.32
#define EOFF   17.312340490667562f
// Ct LDS stride (u16): 390 -> 195 words/row, 195 mod 32 = 3 (odd-ish) => <=2 lanes/bank
#define CTS 390

__device__ __forceinline__ u16 f2bf(float f) {
    unsigned u = __builtin_bit_cast(unsigned, f);
    u += 0x7fffu + ((u >> 16) & 1u);   // round-to-nearest-even
    return (u16)(u >> 16);
}
__device__ __forceinline__ float bf2f(u16 h) {
    return __builtin_bit_cast(float, ((unsigned)h) << 16);
}
__device__ __forceinline__ void gl2lds16(const void* g, void* l) {
    // async global->LDS, 16B/lane; LDS dest = wave-uniform base + lane*16
    using gv = const __attribute__((address_space(1))) void;
    using lv = __attribute__((address_space(3))) void;
    __builtin_amdgcn_global_load_lds((gv*)g, (lv*)l, 16, 0, 0);
}

// -------- 64x64 transpose+cast tile: out[n][k] = bf16(in[k][n]) --------
__device__ __forceinline__ void transpose_tile64(const float* __restrict__ in,
                                                 u16* __restrict__ out,
                                                 int K, int N, int n0, int k0,
                                                 float* tile, int t) {
    int rc = t >> 4, cc = (t & 15) * 4;
#pragma unroll
    for (int p = 0; p < 4; ++p) {
        int k = p * 16 + rc;
        float4 v = *(const float4*)&in[(size_t)(k0 + k) * N + n0 + cc];
        tile[k * 65 + cc] = v.x; tile[k * 65 + cc + 1] = v.y;
        tile[k * 65 + cc + 2] = v.z; tile[k * 65 + cc + 3] = v.w;
    }
    __syncthreads();
    int rn = t >> 3, ck = (t & 7) * 8;
#pragma unroll
    for (int p = 0; p < 2; ++p) {
        int n = p * 32 + rn;
        v8s tv;
#pragma unroll
        for (int j = 0; j < 8; ++j) tv[j] = (short)f2bf(tile[(ck + j) * 65 + n]);
        *(v8s*)&out[(size_t)(n0 + n) * K + k0 + ck] = tv;
    }
}

// ------- prep_all: hidden cast (0..4095) + RoPE tab (4096..4607) + w_qkv^T (4608..10751) -------
__global__ __launch_bounds__(256) void prep_all_kernel(const float* __restrict__ hidden,
                                                       u16* __restrict__ hid_bf,
                                                       const int* __restrict__ positions,
                                                       float* __restrict__ cosT,
                                                       float* __restrict__ sinT,
                                                       const float* __restrict__ w_qkv,
                                                       u16* __restrict__ wqkv_t) {
    __shared__ float tile[64 * 65];
    int b = blockIdx.x;
    if (b < 4096) {
        size_t i = ((size_t)b * 256 + threadIdx.x) * 8;
        float4 a = *(const float4*)&hidden[i];
        float4 c = *(const float4*)&hidden[i + 4];
        v8s tv;
        tv[0] = (short)f2bf(a.x); tv[1] = (short)f2bf(a.y);
        tv[2] = (short)f2bf(a.z); tv[3] = (short)f2bf(a.w);
        tv[4] = (short)f2bf(c.x); tv[5] = (short)f2bf(c.y);
        tv[6] = (short)f2bf(c.z); tv[7] = (short)f2bf(c.w);
        *(v8s*)&hid_bf[i] = tv;
    } else if (b < 4608) {
        int idx = (b - 4096) * 256 + threadIdx.x;   // T*64 entries
        int tp = idx >> 6, i = idx & 63;
        float invf = exp2f(-(float)i * 0.31143075889569023f);  // log2(1e6)/64
        float f = (float)positions[tp] * invf;
        cosT[idx] = cosf(f);
        sinT[idx] = sinf(f);
    } else {
        int bx = b - 4608;                    // 96 x 64 tiles
        int n0 = (bx % 96) * 64, k0 = (bx / 96) * 64;
        transpose_tile64(w_qkv, wqkv_t, 4096, NQKV, n0, k0, tile, threadIdx.x);
    }
}

// ---------------- out-proj GEMM: 128x256 tile, 2-phase, 256 blocks (100% fill) ----------------
// 8 waves (2M x 4N); per-wave C = rows {wm*64+mi*16} (mi<4), cols {wn*64+ni*16} (ni<4).
// 2 phases/K-tile (ks0,ks1), 16 MFMA each. All 6 staging halves of t+1 issued at p1;
// VM0 at p2 sits ~1200cy after issue -> HBM latency covered.
// LDS 96 KiB: buf b at b*24576 u16: A[128][64] @+0, B[256][64] @+8192 (granule-XOR swizzled).
__global__ __launch_bounds__(512, 2) void gemm_out_kernel(
    const u16* __restrict__ A, const u16* __restrict__ Bt, float* __restrict__ C)
{
    __shared__ __align__(16) char smem_raw[98304];
    u16* lds = (u16*)smem_raw;
    const int tid = threadIdx.x;
    const int wave = tid >> 6, lane = tid & 63;
    const int quad = lane >> 4, l15 = lane & 15, lm = l15 & 7;
    const int wm = wave >> 2, wn = wave & 3;
    const int m0 = blockIdx.y * 128, n0 = blockIdx.x * 256;

    v4f acc[4][4];
    v4f z4 = {0.f, 0.f, 0.f, 0.f};
#pragma unroll
    for (int mi = 0; mi < 4; ++mi)
#pragma unroll
        for (int ni = 0; ni < 4; ++ni) acc[mi][ni] = z4;

    const int rsub = lane >> 3;
    const int cg = (lane & 7) ^ rsub;           // pre-swizzled source granule
    const int ch0a = wave * 2, ch0b = wave * 4;
    const int g0 = (quad ^ lm) << 3;
    const int g1 = ((4 + quad) ^ lm) << 3;

    const u16* AgR0 = &A[((size_t)m0 + (ch0a + 0) * 8 + rsub) * KD + cg * 8];
    const u16* AgR1 = &A[((size_t)m0 + (ch0a + 1) * 8 + rsub) * KD + cg * 8];
    const u16* BgR0 = &Bt[((size_t)n0 + (ch0b + 0) * 8 + rsub) * KD + cg * 8];
    const u16* BgR1 = &Bt[((size_t)n0 + (ch0b + 1) * 8 + rsub) * KD + cg * 8];
    const u16* BgR2 = &Bt[((size_t)n0 + (ch0b + 2) * 8 + rsub) * KD + cg * 8];
    const u16* BgR3 = &Bt[((size_t)n0 + (ch0b + 3) * 8 + rsub) * KD + cg * 8];

#define OSTAGE(tt) do { \
    int _b = ((tt) & 1) * 24576; \
    gl2lds16(AgR0 + (size_t)(tt) * 64, &lds[_b + (ch0a + 0) * 512]); \
    gl2lds16(AgR1 + (size_t)(tt) * 64, &lds[_b + (ch0a + 1) * 512]); \
    gl2lds16(BgR0 + (size_t)(tt) * 64, &lds[_b + 8192 + (ch0b + 0) * 512]); \
    gl2lds16(BgR1 + (size_t)(tt) * 64, &lds[_b + 8192 + (ch0b + 1) * 512]); \
    gl2lds16(BgR2 + (size_t)(tt) * 64, &lds[_b + 8192 + (ch0b + 2) * 512]); \
    gl2lds16(BgR3 + (size_t)(tt) * 64, &lds[_b + 8192 + (ch0b + 3) * 512]); \
  } while (0)

    v8s af[4], bfr[4];

#define OPHASE(BO, G, STAGE_CODE, WAIT_CODE) do { \
    _Pragma("unroll") \
    for (int mi = 0; mi < 4; ++mi) \
        af[mi] = *(const v8s*)&lds[(BO) + (wm * 64 + mi * 16 + l15) * 64 + (G)]; \
    _Pragma("unroll") \
    for (int ni = 0; ni < 4; ++ni) \
        bfr[ni] = *(const v8s*)&lds[(BO) + 8192 + (wn * 64 + ni * 16 + l15) * 64 + (G)]; \
    STAGE_CODE; \
    __builtin_amdgcn_s_barrier(); \
    asm volatile("" ::: "memory"); \
    __builtin_amdgcn_s_setprio(1); \
    _Pragma("unroll") \
    for (int mi = 0; mi < 4; ++mi) \
      _Pragma("unroll") \
      for (int ni = 0; ni < 4; ++ni) \
        acc[mi][ni] = __builtin_amdgcn_mfma_f32_16x16x32_bf16( \
            af[mi], bfr[ni], acc[mi][ni], 0, 0, 0); \
    __builtin_amdgcn_s_setprio(0); \
    WAIT_CODE; \
    __builtin_amdgcn_s_barrier(); \
  } while (0)

#define VM0 asm volatile("s_waitcnt vmcnt(0)" ::: "memory")

    OSTAGE(0);
    VM0;
    __builtin_amdgcn_s_barrier();

#pragma unroll 2
    for (int t = 0; t < 62; ++t) {
        const int bo = (t & 1) * 24576;
        OPHASE(bo, g0, { OSTAGE(t + 1); }, {});
        OPHASE(bo, g1, {}, { VM0; });
    }
    // tile 62 (buf 0): stages tile 63
    OPHASE(0, g0, { OSTAGE(63); }, {});
    OPHASE(0, g1, {}, { VM0; });
    // tile 63 (buf 1): pure compute
    OPHASE(24576, g0, {}, {});
    OPHASE(24576, g1, {}, {});
#undef OPHASE
#undef OSTAGE
#undef VM0

#pragma unroll
    for (int mi = 0; mi < 4; ++mi)
#pragma unroll
        for (int ni = 0; ni < 4; ++ni)
#pragma unroll
            for (int r = 0; r < 4; ++r)
                C[(size_t)(m0 + wm * 64 + mi * 16 + quad * 4 + r) * 4096 +
                  (n0 + wn * 64 + ni * 16 + l15)] = acc[mi][ni][r];
}

// ---------------- QKV GEMM: 128x384 tile, 4-phase schedule, 256 blocks (100% fill) ----------------
// 8 waves (2M x 4N); per-wave C = rows {wm*64+mi*16} (mi<4), cols {wn*96+nh*48+ni*16} (ni<3).
// Phases per K-tile: (ks0,nh0)(ks0,nh1)(ks1,nh0)(ks1,nh1); 12 MFMA each; af reused across nh.
// Post-barrier sync is a COMPILER fence only (asm ""): loads are compiler-visible, so
// fine-grained lgkmcnt is auto-inserted per MFMA operand; cross-wave staging visibility
// is carried by vmcnt(0)+barrier (VM0 asm blocks load hoisting past it).
// LDS 128 KiB: buf b at b*32768 u16: A[128][64] @+0, B[384][64] @+8192 (granule-XOR swizzled).
__global__ __launch_bounds__(512, 2) void gemm_qkv384_kernel(
    const u16* __restrict__ A, const u16* __restrict__ Bt,
    const float* __restrict__ qw, const float* __restrict__ kw,
    const float* __restrict__ cosT, const float* __restrict__ sinT,
    u16* __restrict__ Qb, u16* __restrict__ Kb, u16* __restrict__ Vt)
{
    __shared__ __align__(16) char smem_raw[131072];
    u16* lds = (u16*)smem_raw;
    const int tid = threadIdx.x;
    const int wave = tid >> 6, lane = tid & 63;
    const int quad = lane >> 4, l15 = lane & 15, lm = l15 & 7;
    const int wm = wave >> 2, wn = wave & 3;        // 2M x 4N
    const int m0 = blockIdx.y * 128, n0 = blockIdx.x * 384;

    v4f acc[2][4][3];
    v4f z4 = {0.f, 0.f, 0.f, 0.f};
#pragma unroll
    for (int nh = 0; nh < 2; ++nh)
#pragma unroll
        for (int mi = 0; mi < 4; ++mi)
#pragma unroll
            for (int ni = 0; ni < 3; ++ni) acc[nh][mi][ni] = z4;

    const int rsub = lane >> 3;
    const int cg = (lane & 7) ^ rsub;           // pre-swizzled source granule
    const int ch0 = wave * 2;
    const int g0 = (quad ^ lm) << 3;            // u16 offset of ks=0 granule
    const int g1 = ((4 + quad) ^ lm) << 3;      // ks=1

    // hoisted staging row-base pointers (loop-invariant)
    const u16* AgR0 = &A[((size_t)m0 + (ch0 + 0) * 8 + rsub) * KD + cg * 8];
    const u16* AgR1 = &A[((size_t)m0 + (ch0 + 1) * 8 + rsub) * KD + cg * 8];
    const u16* BgR0 = &Bt[((size_t)n0 + (ch0 + 0) * 8 + rsub) * KD + cg * 8];
    const u16* BgR1 = &Bt[((size_t)n0 + (ch0 + 1) * 8 + rsub) * KD + cg * 8];

#define STAGE_AH(tt) do { \
    int _b = ((tt) & 1) * 32768; \
    gl2lds16(AgR0 + (size_t)(tt) * 64, &lds[_b + (ch0 + 0) * 512]); \
    gl2lds16(AgR1 + (size_t)(tt) * 64, &lds[_b + (ch0 + 1) * 512]); \
  } while (0)
#define STAGE_BH(tt, h) do { \
    int _b = ((tt) & 1) * 32768 + 8192; \
    gl2lds16(BgR0 + (size_t)(h) * 128 * KD + (size_t)(tt) * 64, \
             &lds[_b + (h) * 8192 + (ch0 + 0) * 512]); \
    gl2lds16(BgR1 + (size_t)(h) * 128 * KD + (size_t)(tt) * 64, \
             &lds[_b + (h) * 8192 + (ch0 + 1) * 512]); \
  } while (0)

    v8s af[4], bfr[3];

#define PHASEX(BO, G, NHI, RDA, STAGE_CODE, WAIT_CODE) do { \
    if (RDA) { \
      _Pragma("unroll") \
      for (int mi = 0; mi < 4; ++mi) \
        af[mi] = *(const v8s*)&lds[(BO) + (wm * 64 + mi * 16 + l15) * 64 + (G)]; \
    } \
    _Pragma("unroll") \
    for (int ni = 0; ni < 3; ++ni) \
      bfr[ni] = *(const v8s*)&lds[(BO) + 8192 + \
                   (wn * 96 + (NHI) * 48 + ni * 16 + l15) * 64 + (G)]; \
    STAGE_CODE; \
    __builtin_amdgcn_s_barrier(); \
    asm volatile("" ::: "memory"); \
    __builtin_amdgcn_s_setprio(1); \
    _Pragma("unroll") \
    for (int mi = 0; mi < 4; ++mi) \
      _Pragma("unroll") \
      for (int ni = 0; ni < 3; ++ni) \
        acc[NHI][mi][ni] = __builtin_amdgcn_mfma_f32_16x16x32_bf16( \
            af[mi], bfr[ni], acc[NHI][mi][ni], 0, 0, 0); \
    __builtin_amdgcn_s_setprio(0); \
    WAIT_CODE; \
    __builtin_amdgcn_s_barrier(); \
  } while (0)

#define VM0 asm volatile("s_waitcnt vmcnt(0)" ::: "memory")

#define TILE_MAIN(BO, TT1) do { \
    PHASEX(BO, g0, 0, 1, { STAGE_AH(TT1); STAGE_BH(TT1, 0); }, {}); \
    PHASEX(BO, g0, 1, 0, { STAGE_BH(TT1, 1); }, {}); \
    PHASEX(BO, g1, 0, 1, { STAGE_BH(TT1, 2); }, {}); \
    PHASEX(BO, g1, 1, 0, {}, { VM0; }); \
  } while (0)

    // prologue: tile 0 all four halves, then drain
    STAGE_AH(0); STAGE_BH(0, 0); STAGE_BH(0, 1); STAGE_BH(0, 2);
    VM0;
    __builtin_amdgcn_s_barrier();

    // main loop: tiles 0..61 (stages t+1 = 1..62); even trip count for unroll 2
#pragma unroll 2
    for (int t = 0; t < 62; ++t) {
        const int bo = (t & 1) * 32768;
        TILE_MAIN(bo, t + 1);
    }
    // tile 62 (buf 0): stages tile 63
    TILE_MAIN(0, 63);
    // tile 63 (buf 1): pure compute
    PHASEX(32768, g0, 0, 1, {}, {});
    PHASEX(32768, g0, 1, 0, {}, {});
    PHASEX(32768, g1, 0, 1, {}, {});
    PHASEX(32768, g1, 1, 0, {}, {});
#undef TILE_MAIN
#undef PHASEX
#undef STAGE_AH
#undef STAGE_BH
#undef VM0

    // ---- fused epilogue: this block's 384 cols == three heads ----
    u16* Ct = lds;                 // [128][CTS] bf16, aliases staging LDS (dead now)
    const int t0q = blockIdx.y * 128;
    __syncthreads();
#pragma unroll
    for (int nh = 0; nh < 2; ++nh)
#pragma unroll
        for (int mi = 0; mi < 4; ++mi)
#pragma unroll
            for (int ni = 0; ni < 3; ++ni)
#pragma unroll
                for (int r = 0; r < 4; ++r)
                    Ct[(wm * 64 + mi * 16 + quad * 4 + r) * CTS +
                       wn * 96 + nh * 48 + ni * 16 + l15] = f2bf(acc[nh][mi][ni][r]);
    __syncthreads();
    // RMSNorm + RoPE for Q/K heads (rows 0..127 x heads 0..2 = 384 tasks)
    if (tid < 384) {
        const int row = tid & 127, hh = tid >> 7;
        const int head = blockIdx.x * 3 + hh;   // 0..31 q, 32..39 k, 40..47 v
        if (head < 40) {
            const float* w = (head < 32) ? qw : kw;
            float ss = 0.f;
            for (int i = 0; i < 128; ++i) {
                float x = bf2f(Ct[row * CTS + hh * 128 + i]);
                ss += x * x;
            }
            float rs = rsqrtf(ss * (1.0f / 128.0f) + 1e-6f);
            if (head < 32) rs *= QSCALE;   // fold 1/sqrt(HD)*log2e into Q
            const int ti = t0q + row;
            for (int i = 0; i < 64; ++i) {
                float x1 = bf2f(Ct[row * CTS + hh * 128 + i]) * rs * w[i];
                float x2 = bf2f(Ct[row * CTS + hh * 128 + 64 + i]) * rs * w[64 + i];
                float c = cosT[ti * 64 + i], s = sinT[ti * 64 + i];
                Ct[row * CTS + hh * 128 + i]      = f2bf(x1 * c - x2 * s);
                Ct[row * CTS + hh * 128 + 64 + i] = f2bf(x2 * c + x1 * s);
            }
        }
    }
    __syncthreads();
    // store phase: per head, all 512 threads
#pragma unroll
    for (int hh = 0; hh < 3; ++hh) {
        const int head = blockIdx.x * 3 + hh;
        if (head < 40) {
            u16* dst = (head < 32) ? &Qb[((size_t)head * TT + t0q) * HDM]
                                   : &Kb[((size_t)(head - 32) * TT + t0q) * HDM];
            for (int cix = tid; cix < 128 * 16; cix += 512) {
                int row = cix >> 4, part = (cix & 15) * 8;
                v8s tv;
#pragma unroll
                for (int j = 0; j < 8; ++j) tv[j] = (short)Ct[row * CTS + hh * 128 + part + j];
                *(v8s*)&dst[row * HDM + part] = tv;
            }
        } else {
            // V head: write transposed Vt[kv][hd][t]; hd = cix&127 keeps LDS reads
            // conflict-free (consecutive lanes -> consecutive u16 cols)
            const int kvh = head - 40;
            for (int cix = tid; cix < 128 * 16; cix += 512) {
                int hd = cix & 127, tb = cix >> 7;
                v8s tv;
#pragma unroll
                for (int j = 0; j < 8; ++j) tv[j] = (short)Ct[(tb * 8 + j) * CTS + hh * 128 + hd];
                *(v8s*)&Vt[((size_t)kvh * HDM + hd) * TT + t0q + tb * 8] = tv;
            }
        }
    }
}

// ------- attn (blocks 0..1023) + w_o transpose backfill (1024..5119) -------
__global__ __launch_bounds__(256) void attn_plus_kernel(
    const u16* __restrict__ Qb, const u16* __restrict__ Kb,
    const u16* __restrict__ Vt, u16* __restrict__ Ob,
    const float* __restrict__ w_o, u16* __restrict__ wo_t)
{
    __shared__ __align__(16) char smem_raw[40960];
    int tid = threadIdx.x;
    if (blockIdx.x >= 1024) {
        int bx = blockIdx.x - 1024;           // 64 x 64 tiles
        int n0 = (bx & 63) * 64, k0 = (bx >> 6) * 64;
        transpose_tile64(w_o, wo_t, 4096, 4096, n0, k0, (float*)smem_raw, tid);
        return;
    }
    u16* Kl = (u16*)smem_raw;                  // [s][hd] swizzled, 16384 B
    u16* Vl = (u16*)(smem_raw + 16384);        // [hd][s] swizzled, 16384 B
    u16* Pl = (u16*)(smem_raw + 32768);        // per-wave P, swizzled, 8192 B
    int wave = tid >> 6, lane = tid & 63;
    int quad = lane >> 4, l15 = lane & 15;
    int idx = blockIdx.x;
    int h = idx & 31;
    int qb = 31 - (idx >> 5);        // longest blocks dispatch first
    int kv = h >> 2;                 // H/KV = 4
    int q0 = qb * 64;
    int lm = l15 & 7;                // swizzle mask for this lane's row group

    v8s qf[4];
    {
        const u16* qr = &Qb[((size_t)h * TT + q0 + wave * 16 + l15) * HDM];
#pragma unroll
        for (int ks = 0; ks < 4; ++ks) qf[ks] = *(const v8s*)&qr[ks * 32 + quad * 8];
    }

    v4f z4 = {0.f, 0.f, 0.f, 0.f};
    v4f of[8];
#pragma unroll
    for (int i = 0; i < 8; ++i) of[i] = z4;
    float lsum[4];
#pragma unroll
    for (int r = 0; r < 4; ++r) lsum[r] = 0.f;
    u16* Pw = &Pl[wave * 1024];

    for (int s0 = 0; s0 <= q0; s0 += 64) {
        __syncthreads();
#pragma unroll
        for (int c = 0; c < 4; ++c) {
            int ch = wave * 4 + c;
            int rk = ch * 4 + (lane >> 4);              // Kl row (s-local)
            int ck = (lane & 15) ^ (rk & 7);            // logical chunk to fetch
            gl2lds16(&Kb[((size_t)kv * TT + s0 + rk) * HDM + ck * 8], &Kl[ch * 512]);
            int rv = ch * 8 + (lane >> 3);              // Vl row (hd)
            int cv = (lane & 7) ^ (rv & 7);
            gl2lds16(&Vt[((size_t)kv * HDM + rv) * TT + s0 + cv * 8], &Vl[ch * 512]);
        }
        __syncthreads();
        // S = Q @ K^T  (C-layout: row=quad*4+r, col=l15 within n-tile)
        v4f sf[4];
#pragma unroll
        for (int nt = 0; nt < 4; ++nt) {
            v4f cacc = z4;
#pragma unroll
            for (int ks = 0; ks < 4; ++ks)
                cacc = __builtin_amdgcn_mfma_f32_16x16x32_bf16(
                    qf[ks],
                    *(const v8s*)&Kl[(nt * 16 + l15) * 128 + (((ks * 4 + quad) ^ lm) << 3)],
                    cacc, 0, 0, 0);
            sf[nt] = cacc;
        }
        if (s0 == q0) {   // only the diagonal tile needs the causal mask
#pragma unroll
            for (int nt = 0; nt < 4; ++nt) {
                int sg = s0 + nt * 16 + l15;
#pragma unroll
                for (int r = 0; r < 4; ++r) {
                    int qg = q0 + wave * 16 + quad * 4 + r;
                    if (sg > qg) sf[nt][r] = -3.0e38f;
                }
            }
        }
        // fixed-max softmax: p = exp2(S*log2e - 12*log2e); masked -> exp2(-inf)=0
#pragma unroll
        for (int nt = 0; nt < 4; ++nt)
#pragma unroll
            for (int r = 0; r < 4; ++r) {
                float p = exp2f(sf[nt][r] - EOFF);
                sf[nt][r] = p;
                lsum[r] += p;
            }
        // P: C-layout -> swizzled LDS (A-layout source for PV)
#pragma unroll
        for (int nt = 0; nt < 4; ++nt)
#pragma unroll
            for (int r = 0; r < 4; ++r) {
                int row = quad * 4 + r;
                int pch = ((nt << 1) + (l15 >> 3)) ^ (row & 7);
                Pw[row * 64 + pch * 8 + (l15 & 7)] = f2bf(sf[nt][r]);
            }
        // O += P @ V  (no rescale needed with fixed max)
#pragma unroll
        for (int sub = 0; sub < 2; ++sub) {
            v8s pa = *(const v8s*)&Pw[l15 * 64 + ((((sub << 2) + quad) ^ lm) << 3)];
#pragma unroll
            for (int nt = 0; nt < 8; ++nt)
                of[nt] = __builtin_amdgcn_mfma_f32_16x16x32_bf16(
                    pa,
                    *(const v8s*)&Vl[(nt * 16 + l15) * 64 + ((((sub << 2) + quad) ^ lm) << 3)],
                    of[nt], 0, 0, 0);
        }
    }
    // single end-of-kernel l reduction across the 16 col-lanes (same quad group)
#pragma unroll
    for (int off = 1; off < 16; off <<= 1)
#pragma unroll
        for (int r = 0; r < 4; ++r) lsum[r] += __shfl_xor(lsum[r], off, 64);
    float invl[4];
#pragma unroll
    for (int r = 0; r < 4; ++r) invl[r] = 1.0f / lsum[r];
#pragma unroll
    for (int nt = 0; nt < 8; ++nt)
#pragma unroll
        for (int r = 0; r < 4; ++r)
            Ob[(size_t)(q0 + wave * 16 + quad * 4 + r) * (NH * HDM) + h * HDM + nt * 16 + l15] =
                f2bf(of[nt][r] * invl[r]);
}

extern "C" void kernel_launch(void* const* d_in, const int* in_sizes, int n_in,
                              void* d_out, int out_size, void* d_ws, size_t ws_size,
                              hipStream_t stream)
{
    (void)in_sizes; (void)n_in; (void)out_size; (void)ws_size;
    const int*   positions = (const int*)d_in[0];
    const float* hidden    = (const float*)d_in[1];
    const float* w_qkv     = (const float*)d_in[2];
    const float* q_norm_w  = (const float*)d_in[3];
    const float* k_norm_w  = (const float*)d_in[4];
    const float* w_o       = (const float*)d_in[5];
    float* out = (float*)d_out;
    char* ws = (char*)d_ws;
    char* ob = (char*)d_out;

    // ---- d_ws layout (peak = 64 MiB exactly) ----
    u16* hid_bf = (u16*)(ws + 0);                 // [2048][4096] bf16      16 MiB
    u16* attnO  = (u16*)(ws + 0);                 // aliases hid_bf (dead after QKV GEMM)
    u16* wqkv_t = (u16*)(ws + (size_t)16777216);  // [6144][4096] bf16      50.33 MiB (ends at 64 MiB)
    u16* wo_t   = (u16*)(ws + (size_t)16777216);  // [4096][4096] bf16, overwrites wqkv_t after QKV GEMM

    // ---- d_out-hosted scratch (26.2 MiB <= 32 MiB; all dead before final GEMM) ----
    u16*   Qb   = (u16*)(ob + 0);                 // [32][2048][128]     16 MiB
    u16*   Kb   = (u16*)(ob + (size_t)16777216);  // [8][2048][128]      4 MiB
    u16*   Vt   = (u16*)(ob + (size_t)20971520);  // [8][128][2048]      4 MiB
    float* cosT = (float*)(ob + (size_t)25165824);// [2048][64]          0.5 MiB
    float* sinT = (float*)(ob + (size_t)25690112);// [2048][64]          0.5 MiB

    // hidden cast + RoPE tables + w_qkv transpose, one launch
    prep_all_kernel<<<10752, 256, 0, stream>>>(hidden, hid_bf, positions, cosT, sinT,
                                               w_qkv, wqkv_t);

    // fused QKV GEMM: 128x384 tiles, 256 blocks (100% CU fill)
    gemm_qkv384_kernel<<<dim3(16, 16), 512, 0, stream>>>(
        hid_bf, wqkv_t, q_norm_w, k_norm_w, cosT, sinT, Qb, Kb, Vt);

    // attention (1024 blocks) + w_o transpose backfill (4096 blocks), one launch
    attn_plus_kernel<<<5120, 256, 0, stream>>>(Qb, Kb, Vt, attnO, w_o, wo_t);

    // out-proj GEMM: 128x256 tiles, 256 blocks (100% CU fill), fp32 C
    gemm_out_kernel<<<dim3(16, 16), 512, 0, stream>>>(attnO, wo_t, out);
}

// Round 7
// 439.244 us; speedup vs baseline: 1.0964x; 1.0275x over previous
//
#include <hip/hip_runtime.h>

#define TT   2048
#define DD   4096
#define NH   32
#define NKVH 8
#define HDM  128
#define KD   4096
#define NQKV 6144

typedef unsigned short u16;
typedef short v8s __attribute__((ext_vector_type(8)));
typedef float v4f __attribute__((ext_vector_type(4)));

// Q pre-scale: 1/sqrt(128) * log2(e)  (log2e folded so attn uses bare exp2)
#define QSCALE 0.12751744547734565f
// fixed softmax max: 12 * log2(e). Valid because |S| <= |q||k|/sqrt(128) = 11.32
#define EOFF   17.312340490667562f
// Ct LDS stride (u16): 390 -> 195 words/row, 195 mod 32 = 3 (odd-ish) => <=2 lanes/bank
#define CTS 390

__device__ __forceinline__ u16 f2bf(float f) {
    unsigned u = __builtin_bit_cast(unsigned, f);
    u += 0x7fffu + ((u >> 16) & 1u);   // round-to-nearest-even
    return (u16)(u >> 16);
}
__device__ __forceinline__ float bf2f(u16 h) {
    return __builtin_bit_cast(float, ((unsigned)h) << 16);
}
__device__ __forceinline__ void gl2lds16(const void* g, void* l) {
    // async global->LDS, 16B/lane; LDS dest = wave-uniform base + lane*16
    using gv = const __attribute__((address_space(1))) void;
    using lv = __attribute__((address_space(3))) void;
    __builtin_amdgcn_global_load_lds((gv*)g, (lv*)l, 16, 0, 0);
}

// -------- 64x64 transpose+cast tile: out[n][k] = bf16(in[k][n]) --------
__device__ __forceinline__ void transpose_tile64(const float* __restrict__ in,
                                                 u16* __restrict__ out,
                                                 int K, int N, int n0, int k0,
                                                 float* tile, int t) {
    int rc = t >> 4, cc = (t & 15) * 4;
#pragma unroll
    for (int p = 0; p < 4; ++p) {
        int k = p * 16 + rc;
        float4 v = *(const float4*)&in[(size_t)(k0 + k) * N + n0 + cc];
        tile[k * 65 + cc] = v.x; tile[k * 65 + cc + 1] = v.y;
        tile[k * 65 + cc + 2] = v.z; tile[k * 65 + cc + 3] = v.w;
    }
    __syncthreads();
    int rn = t >> 3, ck = (t & 7) * 8;
#pragma unroll
    for (int p = 0; p < 2; ++p) {
        int n = p * 32 + rn;
        v8s tv;
#pragma unroll
        for (int j = 0; j < 8; ++j) tv[j] = (short)f2bf(tile[(ck + j) * 65 + n]);
        *(v8s*)&out[(size_t)(n0 + n) * K + k0 + ck] = tv;
    }
}

// ------- prep_all: hidden cast (0..4095) + RoPE tab (4096..4607) + w_qkv^T (4608..10751) -------
__global__ __launch_bounds__(256) void prep_all_kernel(const float* __restrict__ hidden,
                                                       u16* __restrict__ hid_bf,
                                                       const int* __restrict__ positions,
                                                       float* __restrict__ cosT,
                                                       float* __restrict__ sinT,
                                                       const float* __restrict__ w_qkv,
                                                       u16* __restrict__ wqkv_t) {
    __shared__ float tile[64 * 65];
    int b = blockIdx.x;
    if (b < 4096) {
        size_t i = ((size_t)b * 256 + threadIdx.x) * 8;
        float4 a = *(const float4*)&hidden[i];
        float4 c = *(const float4*)&hidden[i + 4];
        v8s tv;
        tv[0] = (short)f2bf(a.x); tv[1] = (short)f2bf(a.y);
        tv[2] = (short)f2bf(a.z); tv[3] = (short)f2bf(a.w);
        tv[4] = (short)f2bf(c.x); tv[5] = (short)f2bf(c.y);
        tv[6] = (short)f2bf(c.z); tv[7] = (short)f2bf(c.w);
        *(v8s*)&hid_bf[i] = tv;
    } else if (b < 4608) {
        int idx = (b - 4096) * 256 + threadIdx.x;   // T*64 entries
        int tp = idx >> 6, i = idx & 63;
        float invf = exp2f(-(float)i * 0.31143075889569023f);  // log2(1e6)/64
        float f = (float)positions[tp] * invf;
        cosT[idx] = cosf(f);
        sinT[idx] = sinf(f);
    } else {
        int bx = b - 4608;                    // 96 x 64 tiles
        int n0 = (bx % 96) * 64, k0 = (bx / 96) * 64;
        transpose_tile64(w_qkv, wqkv_t, 4096, NQKV, n0, k0, tile, threadIdx.x);
    }
}

// ---------------- out-proj GEMM: 128x256 tile, 1 barrier/K-tile, 256 blocks ----------------
// 8 waves (2M x 4N); per-wave C = rows {wm*64+mi*16} (mi<4), cols {wn*64+ni*16} (ni<4).
// Whole K-tile is ONE scheduling region (16 ds_read_b128 + 32 MFMA + 6 stage issues);
// compiler fine-grains lgkmcnt per MFMA operand and interleaves reads under MFMAs.
// Sync per tile: vmcnt(0) (staging issued a full tile earlier -> already landed) + 1 barrier.
// LDS 96 KiB: buf b at b*24576 u16: A[128][64] @+0, B[256][64] @+8192 (granule-XOR swizzled).
__global__ __launch_bounds__(512, 2) void gemm_out_kernel(
    const u16* __restrict__ A, const u16* __restrict__ Bt, float* __restrict__ C)
{
    __shared__ __align__(16) char smem_raw[98304];
    u16* lds = (u16*)smem_raw;
    const int tid = threadIdx.x;
    const int wave = tid >> 6, lane = tid & 63;
    const int quad = lane >> 4, l15 = lane & 15, lm = l15 & 7;
    const int wm = wave >> 2, wn = wave & 3;
    const int m0 = blockIdx.y * 128, n0 = blockIdx.x * 256;

    v4f acc[4][4];
    v4f z4 = {0.f, 0.f, 0.f, 0.f};
#pragma unroll
    for (int mi = 0; mi < 4; ++mi)
#pragma unroll
        for (int ni = 0; ni < 4; ++ni) acc[mi][ni] = z4;

    const int rsub = lane >> 3;
    const int cg = (lane & 7) ^ rsub;           // pre-swizzled source granule
    const int ch0a = wave * 2, ch0b = wave * 4;
    const int g0 = (quad ^ lm) << 3;
    const int g1 = ((4 + quad) ^ lm) << 3;

    const u16* AgR0 = &A[((size_t)m0 + (ch0a + 0) * 8 + rsub) * KD + cg * 8];
    const u16* AgR1 = &A[((size_t)m0 + (ch0a + 1) * 8 + rsub) * KD + cg * 8];
    const u16* BgR0 = &Bt[((size_t)n0 + (ch0b + 0) * 8 + rsub) * KD + cg * 8];
    const u16* BgR1 = &Bt[((size_t)n0 + (ch0b + 1) * 8 + rsub) * KD + cg * 8];
    const u16* BgR2 = &Bt[((size_t)n0 + (ch0b + 2) * 8 + rsub) * KD + cg * 8];
    const u16* BgR3 = &Bt[((size_t)n0 + (ch0b + 3) * 8 + rsub) * KD + cg * 8];

#define OSTAGE(tt) do { \
    int _b = ((tt) & 1) * 24576; \
    gl2lds16(AgR0 + (size_t)(tt) * 64, &lds[_b + (ch0a + 0) * 512]); \
    gl2lds16(AgR1 + (size_t)(tt) * 64, &lds[_b + (ch0a + 1) * 512]); \
    gl2lds16(BgR0 + (size_t)(tt) * 64, &lds[_b + 8192 + (ch0b + 0) * 512]); \
    gl2lds16(BgR1 + (size_t)(tt) * 64, &lds[_b + 8192 + (ch0b + 1) * 512]); \
    gl2lds16(BgR2 + (size_t)(tt) * 64, &lds[_b + 8192 + (ch0b + 2) * 512]); \
    gl2lds16(BgR3 + (size_t)(tt) * 64, &lds[_b + 8192 + (ch0b + 3) * 512]); \
  } while (0)

#define VM0 asm volatile("s_waitcnt vmcnt(0)" ::: "memory")

#define OTILE(BO, STAGE_CODE) do { \
    STAGE_CODE; \
    v8s af0[4], af1[4], bf0[4], bf1[4]; \
    _Pragma("unroll") \
    for (int mi = 0; mi < 4; ++mi) { \
        const u16* ap = &lds[(BO) + (wm * 64 + mi * 16 + l15) * 64]; \
        af0[mi] = *(const v8s*)&ap[g0]; \
        af1[mi] = *(const v8s*)&ap[g1]; \
    } \
    _Pragma("unroll") \
    for (int ni = 0; ni < 4; ++ni) { \
        const u16* bp = &lds[(BO) + 8192 + (wn * 64 + ni * 16 + l15) * 64]; \
        bf0[ni] = *(const v8s*)&bp[g0]; \
        bf1[ni] = *(const v8s*)&bp[g1]; \
    } \
    _Pragma("unroll") \
    for (int mi = 0; mi < 4; ++mi) \
      _Pragma("unroll") \
      for (int ni = 0; ni < 4; ++ni) { \
        acc[mi][ni] = __builtin_amdgcn_mfma_f32_16x16x32_bf16( \
            af0[mi], bf0[ni], acc[mi][ni], 0, 0, 0); \
        acc[mi][ni] = __builtin_amdgcn_mfma_f32_16x16x32_bf16( \
            af1[mi], bf1[ni], acc[mi][ni], 0, 0, 0); \
      } \
    VM0; \
    __builtin_amdgcn_s_barrier(); \
  } while (0)

    OSTAGE(0);
    VM0;
    __builtin_amdgcn_s_barrier();

#pragma unroll 2
    for (int t = 0; t < 62; ++t) {
        const int bo = (t & 1) * 24576;
        OTILE(bo, { OSTAGE(t + 1); });
    }
    OTILE(0, { OSTAGE(63); });   // tile 62
    OTILE(24576, {});            // tile 63, pure compute
#undef OTILE
#undef OSTAGE
#undef VM0

#pragma unroll
    for (int mi = 0; mi < 4; ++mi)
#pragma unroll
        for (int ni = 0; ni < 4; ++ni)
#pragma unroll
            for (int r = 0; r < 4; ++r)
                C[(size_t)(m0 + wm * 64 + mi * 16 + quad * 4 + r) * 4096 +
                  (n0 + wn * 64 + ni * 16 + l15)] = acc[mi][ni][r];
}

// ---------------- QKV GEMM: 128x384 tile, 1 barrier/K-tile, 256 blocks (100% fill) ----------------
// 8 waves (2M x 4N); per-wave C = rows {wm*64+mi*16} (mi<4), cols {wn*96+nh*48+ni*16} (ni<3).
// Whole K-tile is ONE scheduling region (20 ds_read_b128 + 96 MFMA + 8 stage issues).
// Intra-tile there are NO LDS hazards: reads target buf t&1, staging writes buf (t+1)&1.
// Sync per tile: vmcnt(0) (staging issued a full tile earlier) + 1 barrier (buffer handoff).
// LDS 128 KiB: buf b at b*32768 u16: A[128][64] @+0, B[384][64] @+8192 (granule-XOR swizzled).
__global__ __launch_bounds__(512, 2) void gemm_qkv384_kernel(
    const u16* __restrict__ A, const u16* __restrict__ Bt,
    const float* __restrict__ qw, const float* __restrict__ kw,
    const float* __restrict__ cosT, const float* __restrict__ sinT,
    u16* __restrict__ Qb, u16* __restrict__ Kb, u16* __restrict__ Vt)
{
    __shared__ __align__(16) char smem_raw[131072];
    u16* lds = (u16*)smem_raw;
    const int tid = threadIdx.x;
    const int wave = tid >> 6, lane = tid & 63;
    const int quad = lane >> 4, l15 = lane & 15, lm = l15 & 7;
    const int wm = wave >> 2, wn = wave & 3;        // 2M x 4N
    const int m0 = blockIdx.y * 128, n0 = blockIdx.x * 384;

    v4f acc[2][4][3];
    v4f z4 = {0.f, 0.f, 0.f, 0.f};
#pragma unroll
    for (int nh = 0; nh < 2; ++nh)
#pragma unroll
        for (int mi = 0; mi < 4; ++mi)
#pragma unroll
            for (int ni = 0; ni < 3; ++ni) acc[nh][mi][ni] = z4;

    const int rsub = lane >> 3;
    const int cg = (lane & 7) ^ rsub;           // pre-swizzled source granule
    const int ch0 = wave * 2;
    const int g0 = (quad ^ lm) << 3;            // u16 offset of ks=0 granule
    const int g1 = ((4 + quad) ^ lm) << 3;      // ks=1

    // hoisted staging row-base pointers (loop-invariant)
    const u16* AgR0 = &A[((size_t)m0 + (ch0 + 0) * 8 + rsub) * KD + cg * 8];
    const u16* AgR1 = &A[((size_t)m0 + (ch0 + 1) * 8 + rsub) * KD + cg * 8];
    const u16* BgR0 = &Bt[((size_t)n0 + (ch0 + 0) * 8 + rsub) * KD + cg * 8];
    const u16* BgR1 = &Bt[((size_t)n0 + (ch0 + 1) * 8 + rsub) * KD + cg * 8];

#define STAGE_AH(tt) do { \
    int _b = ((tt) & 1) * 32768; \
    gl2lds16(AgR0 + (size_t)(tt) * 64, &lds[_b + (ch0 + 0) * 512]); \
    gl2lds16(AgR1 + (size_t)(tt) * 64, &lds[_b + (ch0 + 1) * 512]); \
  } while (0)
#define STAGE_BH(tt, h) do { \
    int _b = ((tt) & 1) * 32768 + 8192; \
    gl2lds16(BgR0 + (size_t)(h) * 128 * KD + (size_t)(tt) * 64, \
             &lds[_b + (h) * 8192 + (ch0 + 0) * 512]); \
    gl2lds16(BgR1 + (size_t)(h) * 128 * KD + (size_t)(tt) * 64, \
             &lds[_b + (h) * 8192 + (ch0 + 1) * 512]); \
  } while (0)

#define VM0 asm volatile("s_waitcnt vmcnt(0)" ::: "memory")

#define TILE_BODY(BO, STAGE_CODE) do { \
    STAGE_CODE; \
    v8s af0[4], af1[4], bf0[2][3], bf1[2][3]; \
    _Pragma("unroll") \
    for (int mi = 0; mi < 4; ++mi) { \
        const u16* ap = &lds[(BO) + (wm * 64 + mi * 16 + l15) * 64]; \
        af0[mi] = *(const v8s*)&ap[g0]; \
        af1[mi] = *(const v8s*)&ap[g1]; \
    } \
    _Pragma("unroll") \
    for (int nh = 0; nh < 2; ++nh) \
      _Pragma("unroll") \
      for (int ni = 0; ni < 3; ++ni) { \
        const u16* bp = &lds[(BO) + 8192 + (wn * 96 + nh * 48 + ni * 16 + l15) * 64]; \
        bf0[nh][ni] = *(const v8s*)&bp[g0]; \
        bf1[nh][ni] = *(const v8s*)&bp[g1]; \
      } \
    _Pragma("unroll") \
    for (int nh = 0; nh < 2; ++nh) \
      _Pragma("unroll") \
      for (int mi = 0; mi < 4; ++mi) \
        _Pragma("unroll") \
        for (int ni = 0; ni < 3; ++ni) { \
          acc[nh][mi][ni] = __builtin_amdgcn_mfma_f32_16x16x32_bf16( \
              af0[mi], bf0[nh][ni], acc[nh][mi][ni], 0, 0, 0); \
          acc[nh][mi][ni] = __builtin_amdgcn_mfma_f32_16x16x32_bf16( \
              af1[mi], bf1[nh][ni], acc[nh][mi][ni], 0, 0, 0); \
        } \
    VM0; \
    __builtin_amdgcn_s_barrier(); \
  } while (0)

    // prologue: tile 0 all four halves, then drain
    STAGE_AH(0); STAGE_BH(0, 0); STAGE_BH(0, 1); STAGE_BH(0, 2);
    VM0;
    __builtin_amdgcn_s_barrier();

    // main loop: tiles 0..61 (stages t+1 = 1..62); even trip count for unroll 2
#pragma unroll 2
    for (int t = 0; t < 62; ++t) {
        const int bo = (t & 1) * 32768;
        TILE_BODY(bo, { STAGE_AH(t + 1); STAGE_BH(t + 1, 0);
                        STAGE_BH(t + 1, 1); STAGE_BH(t + 1, 2); });
    }
    // tile 62 (buf 0): stages tile 63
    TILE_BODY(0, { STAGE_AH(63); STAGE_BH(63, 0); STAGE_BH(63, 1); STAGE_BH(63, 2); });
    // tile 63 (buf 1): pure compute
    TILE_BODY(32768, {});
#undef TILE_BODY
#undef STAGE_AH
#undef STAGE_BH
#undef VM0

    // ---- fused epilogue: this block's 384 cols == three heads ----
    u16* Ct = lds;                 // [128][CTS] bf16, aliases staging LDS (dead now)
    const int t0q = blockIdx.y * 128;
    __syncthreads();
#pragma unroll
    for (int nh = 0; nh < 2; ++nh)
#pragma unroll
        for (int mi = 0; mi < 4; ++mi)
#pragma unroll
            for (int ni = 0; ni < 3; ++ni)
#pragma unroll
                for (int r = 0; r < 4; ++r)
                    Ct[(wm * 64 + mi * 16 + quad * 4 + r) * CTS +
                       wn * 96 + nh * 48 + ni * 16 + l15] = f2bf(acc[nh][mi][ni][r]);
    __syncthreads();
    // RMSNorm + RoPE for Q/K heads (rows 0..127 x heads 0..2 = 384 tasks)
    if (tid < 384) {
        const int row = tid & 127, hh = tid >> 7;
        const int head = blockIdx.x * 3 + hh;   // 0..31 q, 32..39 k, 40..47 v
        if (head < 40) {
            const float* w = (head < 32) ? qw : kw;
            float ss = 0.f;
            for (int i = 0; i < 128; ++i) {
                float x = bf2f(Ct[row * CTS + hh * 128 + i]);
                ss += x * x;
            }
            float rs = rsqrtf(ss * (1.0f / 128.0f) + 1e-6f);
            if (head < 32) rs *= QSCALE;   // fold 1/sqrt(HD)*log2e into Q
            const int ti = t0q + row;
            for (int i = 0; i < 64; ++i) {
                float x1 = bf2f(Ct[row * CTS + hh * 128 + i]) * rs * w[i];
                float x2 = bf2f(Ct[row * CTS + hh * 128 + 64 + i]) * rs * w[64 + i];
                float c = cosT[ti * 64 + i], s = sinT[ti * 64 + i];
                Ct[row * CTS + hh * 128 + i]      = f2bf(x1 * c - x2 * s);
                Ct[row * CTS + hh * 128 + 64 + i] = f2bf(x2 * c + x1 * s);
            }
        }
    }
    __syncthreads();
    // store phase: per head, all 512 threads
#pragma unroll
    for (int hh = 0; hh < 3; ++hh) {
        const int head = blockIdx.x * 3 + hh;
        if (head < 40) {
            u16* dst = (head < 32) ? &Qb[((size_t)head * TT + t0q) * HDM]
                                   : &Kb[((size_t)(head - 32) * TT + t0q) * HDM];
            for (int cix = tid; cix < 128 * 16; cix += 512) {
                int row = cix >> 4, part = (cix & 15) * 8;
                v8s tv;
#pragma unroll
                for (int j = 0; j < 8; ++j) tv[j] = (short)Ct[row * CTS + hh * 128 + part + j];
                *(v8s*)&dst[row * HDM + part] = tv;
            }
        } else {
            // V head: write transposed Vt[kv][hd][t]; hd = cix&127 keeps LDS reads
            // conflict-free (consecutive lanes -> consecutive u16 cols)
            const int kvh = head - 40;
            for (int cix = tid; cix < 128 * 16; cix += 512) {
                int hd = cix & 127, tb = cix >> 7;
                v8s tv;
#pragma unroll
                for (int j = 0; j < 8; ++j) tv[j] = (short)Ct[(tb * 8 + j) * CTS + hh * 128 + hd];
                *(v8s*)&Vt[((size_t)kvh * HDM + hd) * TT + t0q + tb * 8] = tv;
            }
        }
    }
}

// ------- attn (blocks 0..1023) + w_o transpose backfill (1024..5119) -------
__global__ __launch_bounds__(256) void attn_plus_kernel(
    const u16* __restrict__ Qb, const u16* __restrict__ Kb,
    const u16* __restrict__ Vt, u16* __restrict__ Ob,
    const float* __restrict__ w_o, u16* __restrict__ wo_t)
{
    __shared__ __align__(16) char smem_raw[40960];
    int tid = threadIdx.x;
    if (blockIdx.x >= 1024) {
        int bx = blockIdx.x - 1024;           // 64 x 64 tiles
        int n0 = (bx & 63) * 64, k0 = (bx >> 6) * 64;
        transpose_tile64(w_o, wo_t, 4096, 4096, n0, k0, (float*)smem_raw, tid);
        return;
    }
    u16* Kl = (u16*)smem_raw;                  // [s][hd] swizzled, 16384 B
    u16* Vl = (u16*)(smem_raw + 16384);        // [hd][s] swizzled, 16384 B
    u16* Pl = (u16*)(smem_raw + 32768);        // per-wave P, swizzled, 8192 B
    int wave = tid >> 6, lane = tid & 63;
    int quad = lane >> 4, l15 = lane & 15;
    int idx = blockIdx.x;
    int h = idx & 31;
    int qb = 31 - (idx >> 5);        // longest blocks dispatch first
    int kv = h >> 2;                 // H/KV = 4
    int q0 = qb * 64;
    int lm = l15 & 7;                // swizzle mask for this lane's row group

    v8s qf[4];
    {
        const u16* qr = &Qb[((size_t)h * TT + q0 + wave * 16 + l15) * HDM];
#pragma unroll
        for (int ks = 0; ks < 4; ++ks) qf[ks] = *(const v8s*)&qr[ks * 32 + quad * 8];
    }

    v4f z4 = {0.f, 0.f, 0.f, 0.f};
    v4f of[8];
#pragma unroll
    for (int i = 0; i < 8; ++i) of[i] = z4;
    float lsum[4];
#pragma unroll
    for (int r = 0; r < 4; ++r) lsum[r] = 0.f;
    u16* Pw = &Pl[wave * 1024];

    for (int s0 = 0; s0 <= q0; s0 += 64) {
        __syncthreads();
#pragma unroll
        for (int c = 0; c < 4; ++c) {
            int ch = wave * 4 + c;
            int rk = ch * 4 + (lane >> 4);              // Kl row (s-local)
            int ck = (lane & 15) ^ (rk & 7);            // logical chunk to fetch
            gl2lds16(&Kb[((size_t)kv * TT + s0 + rk) * HDM + ck * 8], &Kl[ch * 512]);
            int rv = ch * 8 + (lane >> 3);              // Vl row (hd)
            int cv = (lane & 7) ^ (rv & 7);
            gl2lds16(&Vt[((size_t)kv * HDM + rv) * TT + s0 + cv * 8], &Vl[ch * 512]);
        }
        __syncthreads();
        // S = Q @ K^T  (C-layout: row=quad*4+r, col=l15 within n-tile)
        v4f sf[4];
#pragma unroll
        for (int nt = 0; nt < 4; ++nt) {
            v4f cacc = z4;
#pragma unroll
            for (int ks = 0; ks < 4; ++ks)
                cacc = __builtin_amdgcn_mfma_f32_16x16x32_bf16(
                    qf[ks],
                    *(const v8s*)&Kl[(nt * 16 + l15) * 128 + (((ks * 4 + quad) ^ lm) << 3)],
                    cacc, 0, 0, 0);
            sf[nt] = cacc;
        }
        if (s0 == q0) {   // only the diagonal tile needs the causal mask
#pragma unroll
            for (int nt = 0; nt < 4; ++nt) {
                int sg = s0 + nt * 16 + l15;
#pragma unroll
                for (int r = 0; r < 4; ++r) {
                    int qg = q0 + wave * 16 + quad * 4 + r;
                    if (sg > qg) sf[nt][r] = -3.0e38f;
                }
            }
        }
        // fixed-max softmax: p = exp2(S*log2e - 12*log2e); masked -> exp2(-inf)=0
#pragma unroll
        for (int nt = 0; nt < 4; ++nt)
#pragma unroll
            for (int r = 0; r < 4; ++r) {
                float p = exp2f(sf[nt][r] - EOFF);
                sf[nt][r] = p;
                lsum[r] += p;
            }
        // P: C-layout -> swizzled LDS (A-layout source for PV)
#pragma unroll
        for (int nt = 0; nt < 4; ++nt)
#pragma unroll
            for (int r = 0; r < 4; ++r) {
                int row = quad * 4 + r;
                int pch = ((nt << 1) + (l15 >> 3)) ^ (row & 7);
                Pw[row * 64 + pch * 8 + (l15 & 7)] = f2bf(sf[nt][r]);
            }
        // O += P @ V  (no rescale needed with fixed max)
#pragma unroll
        for (int sub = 0; sub < 2; ++sub) {
            v8s pa = *(const v8s*)&Pw[l15 * 64 + ((((sub << 2) + quad) ^ lm) << 3)];
#pragma unroll
            for (int nt = 0; nt < 8; ++nt)
                of[nt] = __builtin_amdgcn_mfma_f32_16x16x32_bf16(
                    pa,
                    *(const v8s*)&Vl[(nt * 16 + l15) * 64 + ((((sub << 2) + quad) ^ lm) << 3)],
                    of[nt], 0, 0, 0);
        }
    }
    // single end-of-kernel l reduction across the 16 col-lanes (same quad group)
#pragma unroll
    for (int off = 1; off < 16; off <<= 1)
#pragma unroll
        for (int r = 0; r < 4; ++r) lsum[r] += __shfl_xor(lsum[r], off, 64);
    float invl[4];
#pragma unroll
    for (int r = 0; r < 4; ++r) invl[r] = 1.0f / lsum[r];
#pragma unroll
    for (int nt = 0; nt < 8; ++nt)
#pragma unroll
        for (int r = 0; r < 4; ++r)
            Ob[(size_t)(q0 + wave * 16 + quad * 4 + r) * (NH * HDM) + h * HDM + nt * 16 + l15] =
                f2bf(of[nt][r] * invl[r]);
}

extern "C" void kernel_launch(void* const* d_in, const int* in_sizes, int n_in,
                              void* d_out, int out_size, void* d_ws, size_t ws_size,
                              hipStream_t stream)
{
    (void)in_sizes; (void)n_in; (void)out_size; (void)ws_size;
    const int*   positions = (const int*)d_in[0];
    const float* hidden    = (const float*)d_in[1];
    const float* w_qkv     = (const float*)d_in[2];
    const float* q_norm_w  = (const float*)d_in[3];
    const float* k_norm_w  = (const float*)d_in[4];
    const float* w_o       = (const float*)d_in[5];
    float* out = (float*)d_out;
    char* ws = (char*)d_ws;
    char* ob = (char*)d_out;

    // ---- d_ws layout (peak = 64 MiB exactly) ----
    u16* hid_bf = (u16*)(ws + 0);                 // [2048][4096] bf16      16 MiB
    u16* attnO  = (u16*)(ws + 0);                 // aliases hid_bf (dead after QKV GEMM)
    u16* wqkv_t = (u16*)(ws + (size_t)16777216);  // [6144][4096] bf16      50.33 MiB (ends at 64 MiB)
    u16* wo_t   = (u16*)(ws + (size_t)16777216);  // [4096][4096] bf16, overwrites wqkv_t after QKV GEMM

    // ---- d_out-hosted scratch (26.2 MiB <= 32 MiB; all dead before final GEMM) ----
    u16*   Qb   = (u16*)(ob + 0);                 // [32][2048][128]     16 MiB
    u16*   Kb   = (u16*)(ob + (size_t)16777216);  // [8][2048][128]      4 MiB
    u16*   Vt   = (u16*)(ob + (size_t)20971520);  // [8][128][2048]      4 MiB
    float* cosT = (float*)(ob + (size_t)25165824);// [2048][64]          0.5 MiB
    float* sinT = (float*)(ob + (size_t)25690112);// [2048][64]          0.5 MiB

    // hidden cast + RoPE tables + w_qkv transpose, one launch
    prep_all_kernel<<<10752, 256, 0, stream>>>(hidden, hid_bf, positions, cosT, sinT,
                                               w_qkv, wqkv_t);

    // fused QKV GEMM: 128x384 tiles, 256 blocks (100% CU fill)
    gemm_qkv384_kernel<<<dim3(16, 16), 512, 0, stream>>>(
        hid_bf, wqkv_t, q_norm_w, k_norm_w, cosT, sinT, Qb, Kb, Vt);

    // attention (1024 blocks) + w_o transpose backfill (4096 blocks), one launch
    attn_plus_kernel<<<5120, 256, 0, stream>>>(Qb, Kb, Vt, attnO, w_o, wo_t);

    // out-proj GEMM: 128x256 tiles, 256 blocks (100% CU fill), fp32 C
    gemm_out_kernel<<<dim3(16, 16), 512, 0, stream>>>(attnO, wo_t, out);
}